// Round 6
// baseline (641.180 us; speedup 1.0000x reference)
//
#include <hip/hip_runtime.h>
#include <cstddef>

// Shapes: B=8, CIN=128, N=2048, K=16, G=4, COUT=256, L=192, CL=48, NL=64, CNL=16
constexpr int NN = 2048;
constexpr int GG = 4;

// ---------------------------------------------------------------------------
// prep_q: Qbuf[g][c2][row] f32 (row<64: M_g[row][c2] = sum_o Wk[o][row]Wq[o][c2];
// row>=64: W2q_g[row-64][c2] = sum_o pe_w2[row-64][o]Wq[o][c2]), o in group g.
// ---------------------------------------------------------------------------
__global__ __launch_bounds__(256) void prep_q(const float* __restrict__ Wq,
                                              const float* __restrict__ Wk,
                                              const float* __restrict__ pe_w2,
                                              float* __restrict__ Qbuf) {
    const int g = blockIdx.x >> 6, c2 = blockIdx.x & 63;
    const int row = threadIdx.x;
    float acc = 0.f;
    if (row < 64) {
        for (int j = 0; j < 48; ++j) {
            const int o = g * 48 + j;
            acc = fmaf(Wk[o * 64 + row], Wq[o * 64 + c2], acc);
        }
    } else {
        const int d = row - 64;
        for (int j = 0; j < 48; ++j) {
            const int o = g * 48 + j;
            acc = fmaf(pe_w2[(size_t)d * 192 + o], Wq[o * 64 + c2], acc);
        }
    }
    Qbuf[((size_t)(g * 64 + c2) << 8) + row] = acc;
}

// ---------------------------------------------------------------------------
// qw_kernel: QW[b][n][g*256+row] = sum_c2 Qbuf[g][c2][row] * a2[b][c2][n].
// Dedicated high-occupancy GEMM (2KB LDS, 8 blocks/CU). All f32 (top-k safe).
// ---------------------------------------------------------------------------
__global__ __launch_bounds__(256, 8) void qw_kernel(
    const float* __restrict__ abs_x, const float* __restrict__ Qbuf,
    float* __restrict__ QW)
{
    const int bt = blockIdx.x;           // b*256 + tile
    const int b  = bt >> 8;
    const int n0 = (bt & 255) << 3;
    const int tid = threadIdx.x;         // = row
    __shared__ float sa2[64][8];
    for (int i = tid; i < 512; i += 256) {
        int c = i >> 3, nl = i & 7;
        sa2[c][nl] = abs_x[((size_t)b * 64 + c) * NN + n0 + nl];
    }
    __syncthreads();
    #pragma unroll
    for (int g = 0; g < 4; ++g) {
        const float* qb = Qbuf + ((size_t)g << 14) + tid;
        float a0 = 0.f, a1 = 0.f, a2v = 0.f, a3 = 0.f, a4 = 0.f, a5 = 0.f, a6 = 0.f, a7 = 0.f;
        for (int c2 = 0; c2 < 64; ++c2) {
            const float qv = qb[c2 << 8];
            const float4 v0 = *(const float4*)&sa2[c2][0];
            const float4 v1 = *(const float4*)&sa2[c2][4];
            a0 = fmaf(qv, v0.x, a0); a1 = fmaf(qv, v0.y, a1);
            a2v = fmaf(qv, v0.z, a2v); a3 = fmaf(qv, v0.w, a3);
            a4 = fmaf(qv, v1.x, a4); a5 = fmaf(qv, v1.y, a5);
            a6 = fmaf(qv, v1.z, a6); a7 = fmaf(qv, v1.w, a7);
        }
        float* op = QW + (((size_t)(b * NN + n0)) << 10) + (g << 8) + tid;
        op[0 << 10] = a0;  op[1 << 10] = a1;  op[(size_t)2 << 10] = a2v; op[(size_t)3 << 10] = a3;
        op[(size_t)4 << 10] = a4; op[(size_t)5 << 10] = a5; op[(size_t)6 << 10] = a6; op[(size_t)7 << 10] = a7;
    }
}

// ---------------------------------------------------------------------------
// local_v6: NTILE=8, ~26KB LDS -> 6 blocks/CU. No Q-stage (reads QW).
// f32 logits end-to-end (top-k safe). cent atomics deferred to kernel end.
// ---------------------------------------------------------------------------
__global__ __launch_bounds__(256, 6) void local_v6(
    const float* __restrict__ x, const float* __restrict__ points,
    const float* __restrict__ Wv,
    const float* __restrict__ pe_w1, const float* __restrict__ pe_b1,
    const int* __restrict__ idx, const float* __restrict__ QW,
    float* __restrict__ out, float* __restrict__ cent)
{
    const int bn = blockIdx.x;           // 2048 blocks
    const int b  = bn >> 8;
    const int n0 = (bn & 255) << 3;
    const int tid = threadIdx.x;

    __shared__ int   sidx[128];
    __shared__ float spts[3][8][16];
    __shared__ __align__(16) float s_union[4 * 8 * 132];  // sq[4][8][65] then sxw[4][8][132]
    __shared__ float spart[128][9];
    __shared__ float satt[8][68];

    float* sq  = s_union;                // sq[(g*8+nl)*65 + c2]
    float* sxw = s_union;                // sxw[(g*8+nl)*132 + c]

    // ---- P0: idx + q~ stage from QW ----
    if (tid < 128) sidx[tid] = idx[((size_t)b * NN + n0) * 16 + tid];
    {
        const float* qsrc = QW + ((size_t)(b * NN + n0) << 10);
        #pragma unroll
        for (int t = 0; t < 8; ++t) {
            const int i = t * 256 + tid;
            const int g = i >> 9, nl = (i >> 6) & 7, c2 = i & 63;
            sq[((g << 3) + nl) * 65 + c2] = qsrc[((size_t)nl << 10) + (g << 8) + c2];
        }
    }
    __syncthreads();

    // ---- P1: points gather ----
    for (int i = tid; i < 384; i += 256) {
        int c = i >> 7, r = i & 127;
        spts[c][r >> 4][r & 15] = points[((size_t)b * 3 + c) * NN + sidx[r]];
    }
    __syncthreads();

    // ---- P2: logits. col=(nl,kk), dh splits c2 (32) and d (96) ranges ----
    {
        const int col = tid & 127, dh = tid >> 7;
        const int nl = col >> 4, kk = col & 15;
        // logitA over c2 in [dh*32, dh*32+32)
        float pA0 = 0.f, pA1 = 0.f, pA2 = 0.f, pA3 = 0.f;
        {
            const float* xp = x + (((size_t)(b * 128 + dh * 32) * NN) + n0 + nl) * 16 + kk;
            const float* q0 = &sq[((0 << 3) + nl) * 65 + dh * 32];
            const float* q1 = &sq[((1 << 3) + nl) * 65 + dh * 32];
            const float* q2 = &sq[((2 << 3) + nl) * 65 + dh * 32];
            const float* q3 = &sq[((3 << 3) + nl) * 65 + dh * 32];
            for (int i = 0; i < 32; ++i) {
                const float xs = xp[0] + xp[(size_t)64 * NN * 16];
                xp += NN * 16;
                pA0 = fmaf(q0[i], xs, pA0);
                pA1 = fmaf(q1[i], xs, pA1);
                pA2 = fmaf(q2[i], xs, pA2);
                pA3 = fmaf(q3[i], xs, pA3);
            }
        }
        // logitB over d in [dh*96, dh*96+96), step 4; w~ streamed from QW
        const float r0 = spts[0][nl][kk] - spts[0][nl][0];
        const float r1 = spts[1][nl][kk] - spts[1][nl][0];
        const float r2 = spts[2][nl][kk] - spts[2][nl][0];
        float pB0 = 0.f, pB1 = 0.f, pB2 = 0.f, pB3 = 0.f;
        const float* wbase = QW + ((size_t)(b * NN + n0 + nl) << 10) + 64;
        const int d0 = dh * 96;
        for (int d = d0; d < d0 + 96; d += 4) {
            const float4 w1a = *(const float4*)&pe_w1[d];
            const float4 w1b = *(const float4*)&pe_w1[192 + d];
            const float4 w1c = *(const float4*)&pe_w1[384 + d];
            const float4 bb  = *(const float4*)&pe_b1[d];
            const float h0 = fmaxf(fmaf(r0, w1a.x, fmaf(r1, w1b.x, fmaf(r2, w1c.x, bb.x))), 0.f);
            const float h1 = fmaxf(fmaf(r0, w1a.y, fmaf(r1, w1b.y, fmaf(r2, w1c.y, bb.y))), 0.f);
            const float h2 = fmaxf(fmaf(r0, w1a.z, fmaf(r1, w1b.z, fmaf(r2, w1c.z, bb.z))), 0.f);
            const float h3 = fmaxf(fmaf(r0, w1a.w, fmaf(r1, w1b.w, fmaf(r2, w1c.w, bb.w))), 0.f);
            const float4 wg0 = *(const float4*)&wbase[(0 << 8) + d];
            const float4 wg1 = *(const float4*)&wbase[(1 << 8) + d];
            const float4 wg2 = *(const float4*)&wbase[(2 << 8) + d];
            const float4 wg3 = *(const float4*)&wbase[(3 << 8) + d];
            pB0 = fmaf(h0, wg0.x, fmaf(h1, wg0.y, fmaf(h2, wg0.z, fmaf(h3, wg0.w, pB0))));
            pB1 = fmaf(h0, wg1.x, fmaf(h1, wg1.y, fmaf(h2, wg1.z, fmaf(h3, wg1.w, pB1))));
            pB2 = fmaf(h0, wg2.x, fmaf(h1, wg2.y, fmaf(h2, wg2.z, fmaf(h3, wg2.w, pB2))));
            pB3 = fmaf(h0, wg3.x, fmaf(h1, wg3.y, fmaf(h2, wg3.z, fmaf(h3, wg3.w, pB3))));
        }
        spart[col][dh * 4 + 0] = pA0 + pB0;
        spart[col][dh * 4 + 1] = pA1 + pB1;
        spart[col][dh * 4 + 2] = pA2 + pB2;
        spart[col][dh * 4 + 3] = pA3 + pB3;
    }
    __syncthreads();

    // ---- P3: softmax over kk per (g,nl) (atomics deferred) ----
    if (tid < 32) {
        const int g = tid >> 3, nl = tid & 7;
        float lg[16], m = -1e30f;
        #pragma unroll
        for (int kk = 0; kk < 16; ++kk) {
            const int col = nl * 16 + kk;
            lg[kk] = spart[col][g] + spart[col][4 + g];
            m = fmaxf(m, lg[kk]);
        }
        float s = 0.f;
        #pragma unroll
        for (int kk = 0; kk < 16; ++kk) { lg[kk] = __expf(lg[kk] - m); s += lg[kk]; }
        const float inv = 1.f / s;
        #pragma unroll
        for (int kk = 0; kk < 16; ++kk) satt[nl][g * 16 + kk] = lg[kk] * inv;
    }
    __syncthreads();

    // ---- P4: xw[g][nl][c] = sum_kk x[c][nl*16+kk]*att ----
    #pragma unroll
    for (int t = 0; t < 4; ++t) {
        const int i2 = t * 256 + tid;
        const int c = i2 >> 3, nl = i2 & 7;
        const float* xp = x + (((size_t)(b * 128 + c) * NN) + n0 + nl) * 16;
        const float4 x0 = *(const float4*)(xp);
        const float4 x1 = *(const float4*)(xp + 4);
        const float4 x2 = *(const float4*)(xp + 8);
        const float4 x3 = *(const float4*)(xp + 12);
        const float xv[16] = {x0.x, x0.y, x0.z, x0.w, x1.x, x1.y, x1.z, x1.w,
                              x2.x, x2.y, x2.z, x2.w, x3.x, x3.y, x3.z, x3.w};
        #pragma unroll
        for (int g = 0; g < 4; ++g) {
            float v = 0.f;
            #pragma unroll
            for (int kk = 0; kk < 16; ++kk) v = fmaf(xv[kk], satt[nl][g * 16 + kk], v);
            sxw[((g << 3) + nl) * 132 + c] = v;
        }
    }
    __syncthreads();

    // ---- P5: out[o][n] = Wv[o,:] . xw[g(o)][nl][:] ----
    #pragma unroll
    for (int rep = 0; rep < 6; ++rep) {
        const int i = rep * 256 + tid;
        const int o = i >> 3, nl = i & 7;
        const int g = o / 48;
        const float* wv  = Wv + (size_t)o * 128;
        const float* xwp = &sxw[((g << 3) + nl) * 132];
        float a = 0.f;
        for (int c = 0; c < 128; c += 4) {
            const float4 w4  = *(const float4*)(wv + c);
            const float4 xw4 = *(const float4*)(xwp + c);
            a = fmaf(w4.x, xw4.x, fmaf(w4.y, xw4.y, fmaf(w4.z, xw4.z, fmaf(w4.w, xw4.w, a))));
        }
        out[(((size_t)b << 8) + o) * NN + n0 + nl] = a;
    }

    // ---- P6: cent atomic scatter (fire-and-forget at kernel end) ----
    if (tid < 32) {
        const int g = tid >> 3, nl = tid & 7;
        #pragma unroll
        for (int kk = 0; kk < 16; ++kk)
            atomicAdd(&cent[((size_t)(b * GG + g) << 11) + sidx[nl * 16 + kk]],
                      satt[nl][g * 16 + kk]);
    }
}

// ---------------------------------------------------------------------------
// local_v5 (fallback if ws too small): passing r5 kernel, unchanged.
// ---------------------------------------------------------------------------
__global__ __launch_bounds__(256, 4) void local_v5(
    const float* __restrict__ x, const float* __restrict__ abs_x,
    const float* __restrict__ points, const float* __restrict__ Wv,
    const float* __restrict__ pe_w1, const float* __restrict__ pe_b1,
    const int* __restrict__ idx, const float* __restrict__ Qbuf,
    float* __restrict__ out, float* __restrict__ cent)
{
    const int bn = blockIdx.x;
    const int b  = bn >> 9;
    const int n0 = (bn & 511) << 2;
    const int tid = threadIdx.x;

    __shared__ int   sidx[64];
    __shared__ float sa2[64][4];
    __shared__ float spts[3][4][16];
    __shared__ float sq[4][4][65];
    __shared__ __align__(16) float s_union[3104];
    __shared__ float spartA[64][17];
    __shared__ float spartB[64][17];
    __shared__ float satt[4][64];

    float* sw  = s_union;
    float* sxw = s_union;

    if (tid < 64) sidx[tid] = idx[((size_t)b * NN + n0) * 16 + tid];
    if (tid < 256) {
        int c = tid >> 2, nl = tid & 3;
        sa2[c][nl] = abs_x[((size_t)b * 64 + c) * NN + n0 + nl];
    }
    __syncthreads();

    if (tid < 192) {
        int c = tid >> 6, r = tid & 63;
        spts[c][r >> 4][r & 15] = points[((size_t)b * 3 + c) * NN + sidx[r]];
    }
    #pragma unroll
    for (int g = 0; g < 4; ++g) {
        const float* qb = Qbuf + ((size_t)g << 14) + tid;
        float a0 = 0.f, a1 = 0.f, a2v = 0.f, a3 = 0.f;
        for (int c2 = 0; c2 < 64; ++c2) {
            const float qv = qb[c2 << 8];
            const float4 av = *(const float4*)&sa2[c2][0];
            a0 = fmaf(qv, av.x, a0); a1 = fmaf(qv, av.y, a1);
            a2v = fmaf(qv, av.z, a2v); a3 = fmaf(qv, av.w, a3);
        }
        if (tid < 64) {
            sq[g][0][tid] = a0; sq[g][1][tid] = a1;
            sq[g][2][tid] = a2v; sq[g][3][tid] = a3;
        } else {
            const int d = tid - 64;
            sw[((g << 2) + 0) * 193 + d] = a0;
            sw[((g << 2) + 1) * 193 + d] = a1;
            sw[((g << 2) + 2) * 193 + d] = a2v;
            sw[((g << 2) + 3) * 193 + d] = a3;
        }
    }
    __syncthreads();

    {
        const int col = tid & 63, ch = tid >> 6;
        const int nl = col >> 4, kk = col & 15;
        const float* xp = x + (((size_t)(b * 128 + ch * 16) * NN) + n0 + nl) * 16 + kk;
        const float* q0 = &sq[0][nl][ch * 16];
        const float* q1 = &sq[1][nl][ch * 16];
        const float* q2 = &sq[2][nl][ch * 16];
        const float* q3 = &sq[3][nl][ch * 16];
        float a0 = 0.f, a1 = 0.f, a2v = 0.f, a3 = 0.f;
        #pragma unroll 4
        for (int i = 0; i < 16; ++i) {
            const float xs = xp[0] + xp[(size_t)64 * NN * 16];
            xp += NN * 16;
            a0 = fmaf(q0[i], xs, a0);
            a1 = fmaf(q1[i], xs, a1);
            a2v = fmaf(q2[i], xs, a2v);
            a3 = fmaf(q3[i], xs, a3);
        }
        spartA[col][ch * 4 + 0] = a0; spartA[col][ch * 4 + 1] = a1;
        spartA[col][ch * 4 + 2] = a2v; spartA[col][ch * 4 + 3] = a3;
    }
    {
        const int col = tid & 63, dh = tid >> 6;
        const int nl = col >> 4, kk = col & 15;
        const float r0 = spts[0][nl][kk] - spts[0][nl][0];
        const float r1 = spts[1][nl][kk] - spts[1][nl][0];
        const float r2 = spts[2][nl][kk] - spts[2][nl][0];
        float p0 = 0.f, p1 = 0.f, p2 = 0.f, p3 = 0.f;
        const int d0 = dh * 48;
        const float* w0 = &sw[((0 << 2) + nl) * 193];
        const float* w1 = &sw[((1 << 2) + nl) * 193];
        const float* w2 = &sw[((2 << 2) + nl) * 193];
        const float* w3 = &sw[((3 << 2) + nl) * 193];
        for (int d = d0; d < d0 + 48; ++d) {
            float h = fmaf(r0, pe_w1[d], fmaf(r1, pe_w1[192 + d], fmaf(r2, pe_w1[384 + d], pe_b1[d])));
            h = fmaxf(h, 0.f);
            p0 = fmaf(h, w0[d], p0);
            p1 = fmaf(h, w1[d], p1);
            p2 = fmaf(h, w2[d], p2);
            p3 = fmaf(h, w3[d], p3);
        }
        spartB[col][dh * 4 + 0] = p0; spartB[col][dh * 4 + 1] = p1;
        spartB[col][dh * 4 + 2] = p2; spartB[col][dh * 4 + 3] = p3;
    }
    __syncthreads();

    float xv[2][16];
    #pragma unroll
    for (int t = 0; t < 2; ++t) {
        const int i2 = t * 256 + tid;
        const int c = i2 >> 2, nl = i2 & 3;
        const float* xp = x + (((size_t)(b * 128 + c) * NN) + n0 + nl) * 16;
        *(float4*)&xv[t][0]  = *(const float4*)(xp);
        *(float4*)&xv[t][4]  = *(const float4*)(xp + 4);
        *(float4*)&xv[t][8]  = *(const float4*)(xp + 8);
        *(float4*)&xv[t][12] = *(const float4*)(xp + 12);
    }

    if (tid < 16) {
        const int g = tid >> 2, nl = tid & 3;
        float lg[16], m = -1e30f;
        #pragma unroll
        for (int kk = 0; kk < 16; ++kk) {
            const int col = nl * 16 + kk;
            lg[kk] = (spartA[col][g] + spartA[col][4 + g] + spartA[col][8 + g] + spartA[col][12 + g])
                   + (spartB[col][g] + spartB[col][4 + g] + spartB[col][8 + g] + spartB[col][12 + g]);
            m = fmaxf(m, lg[kk]);
        }
        float s = 0.f;
        #pragma unroll
        for (int kk = 0; kk < 16; ++kk) { lg[kk] = __expf(lg[kk] - m); s += lg[kk]; }
        const float inv = 1.f / s;
        #pragma unroll
        for (int kk = 0; kk < 16; ++kk) {
            const float a = lg[kk] * inv;
            satt[g][nl * 16 + kk] = a;
            atomicAdd(&cent[((size_t)(b * GG + g) << 11) + sidx[nl * 16 + kk]], a);
        }
    }
    __syncthreads();

    #pragma unroll
    for (int t = 0; t < 2; ++t) {
        const int i2 = t * 256 + tid;
        const int c = i2 >> 2, nl = i2 & 3;
        #pragma unroll
        for (int g = 0; g < 4; ++g) {
            float v = 0.f;
            #pragma unroll
            for (int kk = 0; kk < 16; ++kk) v = fmaf(xv[t][kk], satt[g][nl * 16 + kk], v);
            sxw[(((g << 7) + c) << 2) + nl] = v;
        }
    }
    __syncthreads();

    #pragma unroll
    for (int rep = 0; rep < 3; ++rep) {
        const int i = rep * 256 + tid;
        const int o = i >> 2, nl = i & 3;
        const int g = o / 48;
        const float* wv = Wv + (size_t)o * 128;
        const float* xwp = &sxw[((size_t)(g << 7) << 2) + nl];
        float a = 0.f;
        for (int c = 0; c < 128; c += 4) {
            const float4 w4 = *(const float4*)(wv + c);
            a = fmaf(w4.x, xwp[(c + 0) << 2], a);
            a = fmaf(w4.y, xwp[(c + 1) << 2], a);
            a = fmaf(w4.z, xwp[(c + 2) << 2], a);
            a = fmaf(w4.w, xwp[(c + 3) << 2], a);
        }
        out[(((size_t)b << 8) + o) * NN + n0 + nl] = a;
    }
}

// ---------------------------------------------------------------------------
// Kernel C: per (b,g): top-16 of cent row, then nonlocal prep (unchanged).
// ---------------------------------------------------------------------------
__global__ __launch_bounds__(256) void topk_prep_kernel(
    const float* __restrict__ abs_x, const float* __restrict__ points,
    const float* __restrict__ Wnk, const float* __restrict__ Wnv2,
    const float* __restrict__ npe_w1, const float* __restrict__ npe_b1,
    const float* __restrict__ npe_w2, const float* __restrict__ npe_b2,
    const float* __restrict__ cent,
    float* __restrict__ nkpe, float* __restrict__ nv2j, float* __restrict__ tanhv)
{
    const int bg  = blockIdx.x;
    const int b   = bg >> 2, g = bg & 3;
    const int tid = threadIdx.x;
    __shared__ float sc[2048];
    __shared__ float rv[4];  __shared__ int ri[4];
    __shared__ float svals[16]; __shared__ int sinds[16];
    __shared__ float srel[3][16];
    __shared__ float sh2[16][16];

    for (int i = tid; i < 2048; i += 256) sc[i] = cent[((size_t)bg << 11) + i];
    __syncthreads();
    for (int t = 0; t < 16; ++t) {
        float bv = -1e30f; int bi = 1 << 30;
        for (int i = tid; i < 2048; i += 256) {
            float v = sc[i];
            if (v > bv) { bv = v; bi = i; }
        }
        #pragma unroll
        for (int off = 1; off < 64; off <<= 1) {
            float ov = __shfl_xor(bv, off, 64);
            int   oi = __shfl_xor(bi, off, 64);
            if (ov > bv || (ov == bv && oi < bi)) { bv = ov; bi = oi; }
        }
        if ((tid & 63) == 0) { rv[tid >> 6] = bv; ri[tid >> 6] = bi; }
        __syncthreads();
        if (tid == 0) {
            for (int w = 1; w < 4; ++w)
                if (rv[w] > bv || (rv[w] == bv && ri[w] < bi)) { bv = rv[w]; bi = ri[w]; }
            svals[t] = bv; sinds[t] = bi;
            sc[bi] = -1e30f;
        }
        __syncthreads();
    }

    if (tid < 48) {
        int c = tid >> 4, j = tid & 15;
        srel[c][j] = points[((size_t)b * 3 + c) * NN + sinds[j]]
                   - points[((size_t)b * 3 + c) * NN + sinds[0]];
    }
    __syncthreads();
    {
        int j = tid >> 4, d = tid & 15;
        float a = npe_b1[g * 16 + d];
        #pragma unroll
        for (int c = 0; c < 3; ++c) a = fmaf(srel[c][j], npe_w1[((g * 3 + c) << 4) + d], a);
        sh2[j][d] = fmaxf(a, 0.f);
    }
    __syncthreads();
    {
        int c = tid >> 4, j = tid & 15;
        float a = npe_b2[g * 16 + c];
        #pragma unroll
        for (int d = 0; d < 16; ++d) a = fmaf(sh2[j][d], npe_w2[((g * 16 + d) << 4) + c], a);
        float nk = 0.f, nv = 0.f;
        const int col = sinds[j];
        const float* a2  = abs_x + (size_t)b * 64 * NN + col;
        const float* wkr = Wnk  + ((size_t)(g * 16 + c) << 6);
        const float* wvr = Wnv2 + ((size_t)(g * 16 + c) << 6);
        for (int ci = 0; ci < 64; ++ci) {
            float av = a2[(size_t)ci * NN];
            nk = fmaf(wkr[ci], av, nk);
            nv = fmaf(wvr[ci], av, nv);
        }
        nkpe[((size_t)bg << 8) + (c << 4) + j] = nk + a;
        nv2j[((size_t)bg << 8) + (c << 4) + j] = nv;
    }
    if (tid < 16) tanhv[(bg << 4) + tid] = tanhf(svals[tid]);
}

// ---------------------------------------------------------------------------
// Kernel D: nonlocal branch (unchanged).
// ---------------------------------------------------------------------------
__global__ __launch_bounds__(256) void nonlocal_kernel(
    const float* __restrict__ abs_x,
    const float* __restrict__ Wnq, const float* __restrict__ Wnv1, const float* __restrict__ Wnv2,
    const float* __restrict__ nkpe, const float* __restrict__ nv2j, const float* __restrict__ tanhv,
    float* __restrict__ out)
{
    const int blk = blockIdx.x;
    const int b   = blk >> 5;
    const int n0  = (blk & 31) << 6;
    const int tid = threadIdx.x;
    const int nl  = tid & 63;
    const int g   = tid >> 6;

    __shared__ float sa2[64][64];
    __shared__ float snkpe[4][16][16];
    __shared__ float snv2j[4][16][16];
    __shared__ float stanh[4][16];

    for (int i = tid; i < 64 * 64; i += 256) {
        int ci = i >> 6, c2 = i & 63;
        sa2[ci][c2] = abs_x[((size_t)b * 64 + ci) * NN + n0 + c2];
    }
    for (int i = tid; i < 1024; i += 256) {
        ((float*)snkpe)[i] = nkpe[((size_t)b << 10) + i];
        ((float*)snv2j)[i] = nv2j[((size_t)b << 10) + i];
    }
    if (tid < 64) ((float*)stanh)[tid] = tanhv[(b << 6) + tid];
    __syncthreads();

    float nq[16], nv1[16], nv2[16];
    #pragma unroll
    for (int c = 0; c < 16; ++c) { nq[c] = 0.f; nv1[c] = 0.f; nv2[c] = 0.f; }
    const float* wq  = Wnq  + (size_t)(g << 4) * 64;
    const float* wv1 = Wnv1 + (size_t)(g << 4) * 64;
    const float* wv2 = Wnv2 + (size_t)(g << 4) * 64;
    for (int ci = 0; ci < 64; ++ci) {
        const float a = sa2[ci][nl];
        #pragma unroll
        for (int c = 0; c < 16; ++c) {
            nq[c]  = fmaf(wq [(c << 6) + ci], a, nq[c]);
            nv1[c] = fmaf(wv1[(c << 6) + ci], a, nv1[c]);
            nv2[c] = fmaf(wv2[(c << 6) + ci], a, nv2[c]);
        }
    }

    float lg[16];
    #pragma unroll
    for (int j = 0; j < 16; ++j) {
        float a = 0.f;
        #pragma unroll
        for (int c = 0; c < 16; ++c) a = fmaf(nq[c], snkpe[g][c][j], a);
        lg[j] = a;
    }
    float m = lg[0];
    #pragma unroll
    for (int j = 1; j < 16; ++j) m = fmaxf(m, lg[j]);
    float s = 0.f;
    float w[16];
    #pragma unroll
    for (int j = 0; j < 16; ++j) { w[j] = __expf(lg[j] - m); s += w[j]; }
    const float inv = 1.f / s;
    float ws = 0.f;
    #pragma unroll
    for (int j = 0; j < 16; ++j) { w[j] = w[j] * inv * stanh[g][j]; ws += w[j]; }
    #pragma unroll
    for (int c = 0; c < 16; ++c) {
        float v = (nv1[c] - nv2[c]) * ws;
        #pragma unroll
        for (int j = 0; j < 16; ++j) v = fmaf(w[j], snv2j[g][c][j], v);
        out[(((size_t)b << 8) + 192 + (g << 4) + c) * NN + n0 + nl] = v;
    }
}

// ---------------------------------------------------------------------------
extern "C" void kernel_launch(void* const* d_in, const int* in_sizes, int n_in,
                              void* d_out, int out_size, void* d_ws, size_t ws_size,
                              hipStream_t stream)
{
    (void)in_sizes; (void)n_in; (void)out_size;
    const float* x      = (const float*)d_in[0];
    const float* abs_x  = (const float*)d_in[1];
    const float* points = (const float*)d_in[2];
    const float* Wq     = (const float*)d_in[3];
    const float* Wk     = (const float*)d_in[4];
    const float* Wv     = (const float*)d_in[5];
    const float* Wnq    = (const float*)d_in[6];
    const float* Wnk    = (const float*)d_in[7];
    const float* Wnv1   = (const float*)d_in[8];
    const float* Wnv2   = (const float*)d_in[9];
    const float* pe_w1  = (const float*)d_in[10];
    const float* pe_b1  = (const float*)d_in[11];
    const float* pe_w2  = (const float*)d_in[12];
    // pe_b2 (d_in[13]): constant logit shift per (g,n) -> cancels in softmax
    const float* npe_w1 = (const float*)d_in[14];
    const float* npe_b1 = (const float*)d_in[15];
    const float* npe_w2 = (const float*)d_in[16];
    const float* npe_b2 = (const float*)d_in[17];
    const int*   idx    = (const int*)d_in[18];
    float* out = (float*)d_out;

    // ws layout (floats): cent[65536] | Qbuf[65536] | nkpe[8192] | nv2j[8192] |
    //                     tanh[512] | QW[8*2048*1024]
    float* cent  = (float*)d_ws;
    float* Qbuf  = cent + 65536;
    float* nkpeW = Qbuf + 65536;
    float* nv2jW = nkpeW + 8192;
    float* tanhW = nv2jW + 8192;
    float* QW    = tanhW + 512;

    const size_t need = ((size_t)65536 + 65536 + 8192 + 8192 + 512
                         + (size_t)8 * 2048 * 1024) * sizeof(float);

    hipMemsetAsync(cent, 0, (size_t)65536 * sizeof(float), stream);
    prep_q<<<256, 256, 0, stream>>>(Wq, Wk, pe_w2, Qbuf);
    if (ws_size >= need) {
        qw_kernel<<<2048, 256, 0, stream>>>(abs_x, Qbuf, QW);
        local_v6<<<2048, 256, 0, stream>>>(x, points, Wv, pe_w1, pe_b1,
                                           idx, QW, out, cent);
    } else {
        local_v5<<<4096, 256, 0, stream>>>(x, abs_x, points, Wv, pe_w1, pe_b1,
                                           idx, Qbuf, out, cent);
    }
    topk_prep_kernel<<<32, 256, 0, stream>>>(abs_x, points, Wnk, Wnv2,
                                             npe_w1, npe_b1, npe_w2, npe_b2,
                                             cent, nkpeW, nv2jW, tanhW);
    nonlocal_kernel<<<8 * 32, 256, 0, stream>>>(abs_x, Wnq, Wnv1, Wnv2,
                                                nkpeW, nv2jW, tanhW, out);
}

// Round 7
// 293.321 us; speedup vs baseline: 2.1859x; 2.1859x over previous
//
#include <hip/hip_runtime.h>
#include <cstddef>

// Shapes: B=8, CIN=128, N=2048, K=16, G=4, COUT=256, L=192, CL=48, NL=64, CNL=16
constexpr int NN = 2048;
constexpr int GG = 4;

// ---------------------------------------------------------------------------
// prep_q: Qbuf[g][c2][row] f32 (row<64: M_g[row][c2] = sum_o Wk[o][row]Wq[o][c2];
// row>=64: W2q_g[row-64][c2] = sum_o pe_w2[row-64][o]Wq[o][c2]), o in group g.
// ---------------------------------------------------------------------------
__global__ __launch_bounds__(256) void prep_q(const float* __restrict__ Wq,
                                              const float* __restrict__ Wk,
                                              const float* __restrict__ pe_w2,
                                              float* __restrict__ Qbuf) {
    const int g = blockIdx.x >> 6, c2 = blockIdx.x & 63;
    const int row = threadIdx.x;
    float acc = 0.f;
    if (row < 64) {
        for (int j = 0; j < 48; ++j) {
            const int o = g * 48 + j;
            acc = fmaf(Wk[o * 64 + row], Wq[o * 64 + c2], acc);
        }
    } else {
        const int d = row - 64;
        for (int j = 0; j < 48; ++j) {
            const int o = g * 48 + j;
            acc = fmaf(pe_w2[(size_t)d * 192 + o], Wq[o * 64 + c2], acc);
        }
    }
    Qbuf[((size_t)(g * 64 + c2) << 8) + row] = acc;
}

// ---------------------------------------------------------------------------
// local_v7: v4 skeleton, ~26KB LDS via lifetime-unioned buffers -> 6 blocks/CU.
// All logit math f32 (top-k safe). w~ staged in two 2-group passes.
// Block = (b, 8 n), 256 threads.
// ---------------------------------------------------------------------------
__global__ __launch_bounds__(256, 6) void local_v7(
    const float* __restrict__ x, const float* __restrict__ abs_x,
    const float* __restrict__ points, const float* __restrict__ Wv,
    const float* __restrict__ pe_w1, const float* __restrict__ pe_b1,
    const int* __restrict__ idx, const float* __restrict__ Qbuf,
    float* __restrict__ out, float* __restrict__ cent)
{
    const int bn = blockIdx.x;           // 2048 blocks
    const int b  = bn >> 8;
    const int n0 = (bn & 255) << 3;
    const int tid = threadIdx.x;

    __shared__ int   sidx[128];                       // 0.5 KB (whole kernel)
    __shared__ float sa2[64][8];                      // 2 KB   (P0..P2b)
    __shared__ __align__(16) float s_big[4224];       // 16.9 KB: sq / sw2 / sxw
    __shared__ float spart[128][9];                   // 4.6 KB (P2a..P3)
    __shared__ float s_small[544];                    // 2.2 KB: spts then satt

    float* sq   = s_big;     // sq[((g<<3)+nl)*65 + c2]          (P1..P2a)
    float* sw2  = s_big;     // sw2[((g2<<3)+nl)*196 + d]        (P2b passes)
    float* sxw  = s_big;     // sxw[((g<<3)+nl)*132 + c]         (P4..P5)
    float* spts = s_small;   // spts[(c3*8+nl)*16 + kk]          (P1..P2b)
    float* satt = s_small;   // satt[nl*68 + g*16 + kk]          (P3..P6)

    // ---- P0: idx + a2 ----
    if (tid < 128) sidx[tid] = idx[((size_t)b * NN + n0) * 16 + tid];
    for (int i = tid; i < 512; i += 256) {
        int c = i >> 3, nl = i & 7;
        sa2[c][nl] = abs_x[((size_t)b * 64 + c) * NN + n0 + nl];
    }
    __syncthreads();

    // ---- P1: points gather + q~ stage (thread = (g,row)) ----
    for (int i = tid; i < 384; i += 256) {
        int c3 = i >> 7, r = i & 127;
        spts[(c3 * 8 + (r >> 4)) * 16 + (r & 15)] =
            points[((size_t)b * 3 + c3) * NN + sidx[r]];
    }
    {
        const int g = tid >> 6, row = tid & 63;
        const float* qb = Qbuf + (((size_t)g * 64) << 8) + row;
        float a0 = 0.f, a1 = 0.f, a2v = 0.f, a3 = 0.f,
              a4 = 0.f, a5 = 0.f, a6 = 0.f, a7 = 0.f;
        for (int c2 = 0; c2 < 64; ++c2) {
            const float qv = qb[c2 << 8];
            const float4 v0 = *(const float4*)&sa2[c2][0];
            const float4 v1 = *(const float4*)&sa2[c2][4];
            a0 = fmaf(qv, v0.x, a0); a1 = fmaf(qv, v0.y, a1);
            a2v = fmaf(qv, v0.z, a2v); a3 = fmaf(qv, v0.w, a3);
            a4 = fmaf(qv, v1.x, a4); a5 = fmaf(qv, v1.y, a5);
            a6 = fmaf(qv, v1.z, a6); a7 = fmaf(qv, v1.w, a7);
        }
        const int base = (g << 3) * 65 + row;
        sq[base + 0 * 65] = a0; sq[base + 1 * 65] = a1;
        sq[base + 2 * 65] = a2v; sq[base + 3 * 65] = a3;
        sq[base + 4 * 65] = a4; sq[base + 5 * 65] = a5;
        sq[base + 6 * 65] = a6; sq[base + 7 * 65] = a7;
    }
    __syncthreads();

    // common thread mapping for P2a/P2b
    const int col = tid & 127, dh = tid >> 7;
    const int nlc = col >> 4, kkc = col & 15;

    // ---- P2a: logitA partials -> spart[col][dh*4+g] ----
    {
        const float* xp = x + (((size_t)(b * 128 + dh * 32) * NN) + n0 + nlc) * 16 + kkc;
        const float* q0 = &sq[((0 << 3) + nlc) * 65 + dh * 32];
        const float* q1 = &sq[((1 << 3) + nlc) * 65 + dh * 32];
        const float* q2 = &sq[((2 << 3) + nlc) * 65 + dh * 32];
        const float* q3 = &sq[((3 << 3) + nlc) * 65 + dh * 32];
        float a0 = 0.f, a1 = 0.f, a2v = 0.f, a3 = 0.f;
        for (int i = 0; i < 32; ++i) {
            const float xs = xp[0] + xp[(size_t)64 * NN * 16];
            xp += NN * 16;
            a0 = fmaf(q0[i], xs, a0);
            a1 = fmaf(q1[i], xs, a1);
            a2v = fmaf(q2[i], xs, a2v);
            a3 = fmaf(q3[i], xs, a3);
        }
        spart[col][dh * 4 + 0] = a0; spart[col][dh * 4 + 1] = a1;
        spart[col][dh * 4 + 2] = a2v; spart[col][dh * 4 + 3] = a3;
    }
    __syncthreads();   // sq dead; s_big free for sw2

    // ---- P2b: logitB in two 2-group passes (w~ staged 12.5 KB at a time) ----
    const float r0 = spts[(0 * 8 + nlc) * 16 + kkc] - spts[(0 * 8 + nlc) * 16];
    const float r1 = spts[(1 * 8 + nlc) * 16 + kkc] - spts[(1 * 8 + nlc) * 16];
    const float r2 = spts[(2 * 8 + nlc) * 16 + kkc] - spts[(2 * 8 + nlc) * 16];
    #pragma unroll
    for (int p = 0; p < 2; ++p) {
        if (tid < 192) {            // stage w~[2p..2p+1][tid(d)][8 nl]
            const int d = tid;
            float w00=0.f,w01=0.f,w02=0.f,w03=0.f,w04=0.f,w05=0.f,w06=0.f,w07=0.f;
            float w10=0.f,w11=0.f,w12=0.f,w13=0.f,w14=0.f,w15=0.f,w16=0.f,w17=0.f;
            const float* qb0 = Qbuf + (((size_t)(2 * p + 0) * 64) << 8) + 64 + d;
            const float* qb1 = Qbuf + (((size_t)(2 * p + 1) * 64) << 8) + 64 + d;
            for (int c2 = 0; c2 < 64; ++c2) {
                const float qv0 = qb0[c2 << 8];
                const float qv1 = qb1[c2 << 8];
                const float4 v0 = *(const float4*)&sa2[c2][0];
                const float4 v1 = *(const float4*)&sa2[c2][4];
                w00 = fmaf(qv0, v0.x, w00); w01 = fmaf(qv0, v0.y, w01);
                w02 = fmaf(qv0, v0.z, w02); w03 = fmaf(qv0, v0.w, w03);
                w04 = fmaf(qv0, v1.x, w04); w05 = fmaf(qv0, v1.y, w05);
                w06 = fmaf(qv0, v1.z, w06); w07 = fmaf(qv0, v1.w, w07);
                w10 = fmaf(qv1, v0.x, w10); w11 = fmaf(qv1, v0.y, w11);
                w12 = fmaf(qv1, v0.z, w12); w13 = fmaf(qv1, v0.w, w13);
                w14 = fmaf(qv1, v1.x, w14); w15 = fmaf(qv1, v1.y, w15);
                w16 = fmaf(qv1, v1.z, w16); w17 = fmaf(qv1, v1.w, w17);
            }
            sw2[(0 * 8 + 0) * 196 + d] = w00; sw2[(0 * 8 + 1) * 196 + d] = w01;
            sw2[(0 * 8 + 2) * 196 + d] = w02; sw2[(0 * 8 + 3) * 196 + d] = w03;
            sw2[(0 * 8 + 4) * 196 + d] = w04; sw2[(0 * 8 + 5) * 196 + d] = w05;
            sw2[(0 * 8 + 6) * 196 + d] = w06; sw2[(0 * 8 + 7) * 196 + d] = w07;
            sw2[(1 * 8 + 0) * 196 + d] = w10; sw2[(1 * 8 + 1) * 196 + d] = w11;
            sw2[(1 * 8 + 2) * 196 + d] = w12; sw2[(1 * 8 + 3) * 196 + d] = w13;
            sw2[(1 * 8 + 4) * 196 + d] = w14; sw2[(1 * 8 + 5) * 196 + d] = w15;
            sw2[(1 * 8 + 6) * 196 + d] = w16; sw2[(1 * 8 + 7) * 196 + d] = w17;
        }
        __syncthreads();
        {
            float pB0 = 0.f, pB1 = 0.f;
            const float* w0 = &sw2[(0 * 8 + nlc) * 196];
            const float* w1 = &sw2[(1 * 8 + nlc) * 196];
            const int d0 = dh * 96;
            for (int d = d0; d < d0 + 96; d += 4) {
                const float4 w1a = *(const float4*)&pe_w1[d];
                const float4 w1b = *(const float4*)&pe_w1[192 + d];
                const float4 w1c = *(const float4*)&pe_w1[384 + d];
                const float4 bb  = *(const float4*)&pe_b1[d];
                const float h0 = fmaxf(fmaf(r0, w1a.x, fmaf(r1, w1b.x, fmaf(r2, w1c.x, bb.x))), 0.f);
                const float h1 = fmaxf(fmaf(r0, w1a.y, fmaf(r1, w1b.y, fmaf(r2, w1c.y, bb.y))), 0.f);
                const float h2 = fmaxf(fmaf(r0, w1a.z, fmaf(r1, w1b.z, fmaf(r2, w1c.z, bb.z))), 0.f);
                const float h3 = fmaxf(fmaf(r0, w1a.w, fmaf(r1, w1b.w, fmaf(r2, w1c.w, bb.w))), 0.f);
                const float4 wa = *(const float4*)&w0[d];
                const float4 wb = *(const float4*)&w1[d];
                pB0 = fmaf(h0, wa.x, fmaf(h1, wa.y, fmaf(h2, wa.z, fmaf(h3, wa.w, pB0))));
                pB1 = fmaf(h0, wb.x, fmaf(h1, wb.y, fmaf(h2, wb.z, fmaf(h3, wb.w, pB1))));
            }
            spart[col][dh * 4 + 2 * p + 0] += pB0;
            spart[col][dh * 4 + 2 * p + 1] += pB1;
        }
        __syncthreads();
    }

    // ---- P3: softmax over kk per (g,nl) ----
    if (tid < 32) {
        const int g = tid >> 3, nl = tid & 7;
        float lg[16], m = -1e30f;
        #pragma unroll
        for (int kk = 0; kk < 16; ++kk) {
            const int cc = nl * 16 + kk;
            lg[kk] = spart[cc][g] + spart[cc][4 + g];
            m = fmaxf(m, lg[kk]);
        }
        float s = 0.f;
        #pragma unroll
        for (int kk = 0; kk < 16; ++kk) { lg[kk] = __expf(lg[kk] - m); s += lg[kk]; }
        const float inv = 1.f / s;
        #pragma unroll
        for (int kk = 0; kk < 16; ++kk) satt[nl * 68 + g * 16 + kk] = lg[kk] * inv;
    }
    __syncthreads();

    // ---- P4: xw[g][nl][c] = sum_kk x[c][nl*16+kk]*att ----
    #pragma unroll
    for (int t = 0; t < 4; ++t) {
        const int i2 = t * 256 + tid;
        const int c = i2 >> 3, nl = i2 & 7;
        const float* xp = x + (((size_t)(b * 128 + c) * NN) + n0 + nl) * 16;
        const float4 x0 = *(const float4*)(xp);
        const float4 x1 = *(const float4*)(xp + 4);
        const float4 x2 = *(const float4*)(xp + 8);
        const float4 x3 = *(const float4*)(xp + 12);
        const float* at = &satt[nl * 68];
        #pragma unroll
        for (int g = 0; g < 4; ++g) {
            const float* a = at + g * 16;
            float v = 0.f;
            v = fmaf(x0.x, a[0],  v); v = fmaf(x0.y, a[1],  v);
            v = fmaf(x0.z, a[2],  v); v = fmaf(x0.w, a[3],  v);
            v = fmaf(x1.x, a[4],  v); v = fmaf(x1.y, a[5],  v);
            v = fmaf(x1.z, a[6],  v); v = fmaf(x1.w, a[7],  v);
            v = fmaf(x2.x, a[8],  v); v = fmaf(x2.y, a[9],  v);
            v = fmaf(x2.z, a[10], v); v = fmaf(x2.w, a[11], v);
            v = fmaf(x3.x, a[12], v); v = fmaf(x3.y, a[13], v);
            v = fmaf(x3.z, a[14], v); v = fmaf(x3.w, a[15], v);
            sxw[((g << 3) + nl) * 132 + c] = v;
        }
    }
    __syncthreads();

    // ---- P5: out[o][n] = Wv[o,:] . xw[g(o)][nl][:] ----
    #pragma unroll
    for (int rep = 0; rep < 6; ++rep) {
        const int i = rep * 256 + tid;
        const int o = i >> 3, nl = i & 7;
        const int g = o / 48;
        const float* wv  = Wv + (size_t)o * 128;
        const float* xwp = &sxw[((g << 3) + nl) * 132];
        float a = 0.f;
        for (int c = 0; c < 128; c += 4) {
            const float4 w4  = *(const float4*)(wv + c);
            const float4 xw4 = *(const float4*)(xwp + c);
            a = fmaf(w4.x, xw4.x, fmaf(w4.y, xw4.y, fmaf(w4.z, xw4.z, fmaf(w4.w, xw4.w, a))));
        }
        out[(((size_t)b << 8) + o) * NN + n0 + nl] = a;
    }

    // ---- P6: deferred cent atomic scatter ----
    if (tid < 32) {
        const int g = tid >> 3, nl = tid & 7;
        #pragma unroll
        for (int kk = 0; kk < 16; ++kk)
            atomicAdd(&cent[((size_t)(b * GG + g) << 11) + sidx[nl * 16 + kk]],
                      satt[nl * 68 + g * 16 + kk]);
    }
}

// ---------------------------------------------------------------------------
// Kernel C: per (b,g): top-16 of cent row (512 threads), then nonlocal prep.
// ---------------------------------------------------------------------------
__global__ __launch_bounds__(512) void topk_prep_kernel(
    const float* __restrict__ abs_x, const float* __restrict__ points,
    const float* __restrict__ Wnk, const float* __restrict__ Wnv2,
    const float* __restrict__ npe_w1, const float* __restrict__ npe_b1,
    const float* __restrict__ npe_w2, const float* __restrict__ npe_b2,
    const float* __restrict__ cent,
    float* __restrict__ nkpe, float* __restrict__ nv2j, float* __restrict__ tanhv)
{
    const int bg  = blockIdx.x;
    const int b   = bg >> 2, g = bg & 3;
    const int tid = threadIdx.x;
    __shared__ float sc[2048];
    __shared__ float rv[8];  __shared__ int ri[8];
    __shared__ float svals[16]; __shared__ int sinds[16];
    __shared__ float srel[3][16];
    __shared__ float sh2[16][16];

    for (int i = tid; i < 2048; i += 512) sc[i] = cent[((size_t)bg << 11) + i];
    __syncthreads();
    for (int t = 0; t < 16; ++t) {
        float bv = -1e30f; int bi = 1 << 30;
        for (int i = tid; i < 2048; i += 512) {      // ascending -> lowest idx on ties
            float v = sc[i];
            if (v > bv) { bv = v; bi = i; }
        }
        #pragma unroll
        for (int off = 1; off < 64; off <<= 1) {
            float ov = __shfl_xor(bv, off, 64);
            int   oi = __shfl_xor(bi, off, 64);
            if (ov > bv || (ov == bv && oi < bi)) { bv = ov; bi = oi; }
        }
        if ((tid & 63) == 0) { rv[tid >> 6] = bv; ri[tid >> 6] = bi; }
        __syncthreads();
        if (tid == 0) {
            for (int w = 1; w < 8; ++w)
                if (rv[w] > bv || (rv[w] == bv && ri[w] < bi)) { bv = rv[w]; bi = ri[w]; }
            svals[t] = bv; sinds[t] = bi;
            sc[bi] = -1e30f;
        }
        __syncthreads();
    }

    if (tid < 48) {
        int c = tid >> 4, j = tid & 15;
        srel[c][j] = points[((size_t)b * 3 + c) * NN + sinds[j]]
                   - points[((size_t)b * 3 + c) * NN + sinds[0]];
    }
    __syncthreads();
    if (tid < 256) {
        int j = tid >> 4, d = tid & 15;
        float a = npe_b1[g * 16 + d];
        #pragma unroll
        for (int c = 0; c < 3; ++c) a = fmaf(srel[c][j], npe_w1[((g * 3 + c) << 4) + d], a);
        sh2[j][d] = fmaxf(a, 0.f);
    }
    __syncthreads();
    if (tid < 256) {
        int c = tid >> 4, j = tid & 15;
        float a = npe_b2[g * 16 + c];
        #pragma unroll
        for (int d = 0; d < 16; ++d) a = fmaf(sh2[j][d], npe_w2[((g * 16 + d) << 4) + c], a);
        float nk = 0.f, nv = 0.f;
        const int colj = sinds[j];
        const float* a2  = abs_x + (size_t)b * 64 * NN + colj;
        const float* wkr = Wnk  + ((size_t)(g * 16 + c) << 6);
        const float* wvr = Wnv2 + ((size_t)(g * 16 + c) << 6);
        for (int ci = 0; ci < 64; ++ci) {
            float av = a2[(size_t)ci * NN];
            nk = fmaf(wkr[ci], av, nk);
            nv = fmaf(wvr[ci], av, nv);
        }
        nkpe[((size_t)bg << 8) + (c << 4) + j] = nk + a;
        nv2j[((size_t)bg << 8) + (c << 4) + j] = nv;
    }
    if (tid < 16) tanhv[(bg << 4) + tid] = tanhf(svals[tid]);
}

// ---------------------------------------------------------------------------
// Kernel D: nonlocal branch (unchanged).
// ---------------------------------------------------------------------------
__global__ __launch_bounds__(256) void nonlocal_kernel(
    const float* __restrict__ abs_x,
    const float* __restrict__ Wnq, const float* __restrict__ Wnv1, const float* __restrict__ Wnv2,
    const float* __restrict__ nkpe, const float* __restrict__ nv2j, const float* __restrict__ tanhv,
    float* __restrict__ out)
{
    const int blk = blockIdx.x;
    const int b   = blk >> 5;
    const int n0  = (blk & 31) << 6;
    const int tid = threadIdx.x;
    const int nl  = tid & 63;
    const int g   = tid >> 6;

    __shared__ float sa2[64][64];
    __shared__ float snkpe[4][16][16];
    __shared__ float snv2j[4][16][16];
    __shared__ float stanh[4][16];

    for (int i = tid; i < 64 * 64; i += 256) {
        int ci = i >> 6, c2 = i & 63;
        sa2[ci][c2] = abs_x[((size_t)b * 64 + ci) * NN + n0 + c2];
    }
    for (int i = tid; i < 1024; i += 256) {
        ((float*)snkpe)[i] = nkpe[((size_t)b << 10) + i];
        ((float*)snv2j)[i] = nv2j[((size_t)b << 10) + i];
    }
    if (tid < 64) ((float*)stanh)[tid] = tanhv[(b << 6) + tid];
    __syncthreads();

    float nq[16], nv1[16], nv2[16];
    #pragma unroll
    for (int c = 0; c < 16; ++c) { nq[c] = 0.f; nv1[c] = 0.f; nv2[c] = 0.f; }
    const float* wq  = Wnq  + (size_t)(g << 4) * 64;
    const float* wv1 = Wnv1 + (size_t)(g << 4) * 64;
    const float* wv2 = Wnv2 + (size_t)(g << 4) * 64;
    for (int ci = 0; ci < 64; ++ci) {
        const float a = sa2[ci][nl];
        #pragma unroll
        for (int c = 0; c < 16; ++c) {
            nq[c]  = fmaf(wq [(c << 6) + ci], a, nq[c]);
            nv1[c] = fmaf(wv1[(c << 6) + ci], a, nv1[c]);
            nv2[c] = fmaf(wv2[(c << 6) + ci], a, nv2[c]);
        }
    }

    float lg[16];
    #pragma unroll
    for (int j = 0; j < 16; ++j) {
        float a = 0.f;
        #pragma unroll
        for (int c = 0; c < 16; ++c) a = fmaf(nq[c], snkpe[g][c][j], a);
        lg[j] = a;
    }
    float m = lg[0];
    #pragma unroll
    for (int j = 1; j < 16; ++j) m = fmaxf(m, lg[j]);
    float s = 0.f;
    float w[16];
    #pragma unroll
    for (int j = 0; j < 16; ++j) { w[j] = __expf(lg[j] - m); s += w[j]; }
    const float inv = 1.f / s;
    float ws = 0.f;
    #pragma unroll
    for (int j = 0; j < 16; ++j) { w[j] = w[j] * inv * stanh[g][j]; ws += w[j]; }
    #pragma unroll
    for (int c = 0; c < 16; ++c) {
        float v = (nv1[c] - nv2[c]) * ws;
        #pragma unroll
        for (int j = 0; j < 16; ++j) v = fmaf(w[j], snv2j[g][c][j], v);
        out[(((size_t)b << 8) + 192 + (g << 4) + c) * NN + n0 + nl] = v;
    }
}

// ---------------------------------------------------------------------------
extern "C" void kernel_launch(void* const* d_in, const int* in_sizes, int n_in,
                              void* d_out, int out_size, void* d_ws, size_t ws_size,
                              hipStream_t stream)
{
    (void)in_sizes; (void)n_in; (void)out_size; (void)ws_size;
    const float* x      = (const float*)d_in[0];
    const float* abs_x  = (const float*)d_in[1];
    const float* points = (const float*)d_in[2];
    const float* Wq     = (const float*)d_in[3];
    const float* Wk     = (const float*)d_in[4];
    const float* Wv     = (const float*)d_in[5];
    const float* Wnq    = (const float*)d_in[6];
    const float* Wnk    = (const float*)d_in[7];
    const float* Wnv1   = (const float*)d_in[8];
    const float* Wnv2   = (const float*)d_in[9];
    const float* pe_w1  = (const float*)d_in[10];
    const float* pe_b1  = (const float*)d_in[11];
    const float* pe_w2  = (const float*)d_in[12];
    // pe_b2 (d_in[13]): constant logit shift per (g,n) -> cancels in softmax
    const float* npe_w1 = (const float*)d_in[14];
    const float* npe_b1 = (const float*)d_in[15];
    const float* npe_w2 = (const float*)d_in[16];
    const float* npe_b2 = (const float*)d_in[17];
    const int*   idx    = (const int*)d_in[18];
    float* out = (float*)d_out;

    // ws layout (floats): cent[65536] | Qbuf[65536] | nkpe[8192] | nv2j[8192] | tanh[512]
    float* cent  = (float*)d_ws;
    float* Qbuf  = cent + 65536;
    float* nkpeW = Qbuf + 65536;
    float* nv2jW = nkpeW + 8192;
    float* tanhW = nv2jW + 8192;

    hipMemsetAsync(cent, 0, (size_t)65536 * sizeof(float), stream);
    prep_q<<<256, 256, 0, stream>>>(Wq, Wk, pe_w2, Qbuf);
    local_v7<<<2048, 256, 0, stream>>>(x, abs_x, points, Wv, pe_w1, pe_b1,
                                       idx, Qbuf, out, cent);
    topk_prep_kernel<<<32, 512, 0, stream>>>(abs_x, points, Wnk, Wnv2,
                                             npe_w1, npe_b1, npe_w2, npe_b2,
                                             cent, nkpeW, nv2jW, tanhW);
    nonlocal_kernel<<<8 * 32, 256, 0, stream>>>(abs_x, Wnq, Wnv1, Wnv2,
                                                nkpeW, nv2jW, tanhW, out);
}

// Round 8
// 261.966 us; speedup vs baseline: 2.4476x; 1.1197x over previous
//
#include <hip/hip_runtime.h>
#include <cstddef>

// Shapes: B=8, CIN=128, N=2048, K=16, G=4, COUT=256, L=192, CL=48, NL=64, CNL=16
constexpr int NN = 2048;
constexpr int GG = 4;

// ---------------------------------------------------------------------------
// prep_q: Qbuf[g][c2][row] f32 (row<64: M_g[row][c2] = sum_o Wk[o][row]Wq[o][c2];
// row>=64: W2q_g[row-64][c2] = sum_o pe_w2[row-64][o]Wq[o][c2]), o in group g.
// ---------------------------------------------------------------------------
__global__ __launch_bounds__(256) void prep_q(const float* __restrict__ Wq,
                                              const float* __restrict__ Wk,
                                              const float* __restrict__ pe_w2,
                                              float* __restrict__ Qbuf) {
    const int g = blockIdx.x >> 6, c2 = blockIdx.x & 63;
    const int row = threadIdx.x;
    float acc = 0.f;
    if (row < 64) {
        for (int j = 0; j < 48; ++j) {
            const int o = g * 48 + j;
            acc = fmaf(Wk[o * 64 + row], Wq[o * 64 + c2], acc);
        }
    } else {
        const int d = row - 64;
        for (int j = 0; j < 48; ++j) {
            const int o = g * 48 + j;
            acc = fmaf(pe_w2[(size_t)d * 192 + o], Wq[o * 64 + c2], acc);
        }
    }
    Qbuf[((size_t)(g * 64 + c2) << 8) + row] = acc;
}

// ---------------------------------------------------------------------------
// local_v7b: v7 structure, launch_bounds(256,5) -> VGPR cap ~102, NO spills.
// ~26KB LDS. All logit math f32 (top-k safe). Block = (b, 8 n), 256 threads.
// ---------------------------------------------------------------------------
__global__ __launch_bounds__(256, 5) void local_v7b(
    const float* __restrict__ x, const float* __restrict__ abs_x,
    const float* __restrict__ points, const float* __restrict__ Wv,
    const float* __restrict__ pe_w1, const float* __restrict__ pe_b1,
    const int* __restrict__ idx, const float* __restrict__ Qbuf,
    float* __restrict__ out, float* __restrict__ cent)
{
    const int bn = blockIdx.x;           // 2048 blocks
    const int b  = bn >> 8;
    const int n0 = (bn & 255) << 3;
    const int tid = threadIdx.x;

    __shared__ int   sidx[128];                       // 0.5 KB (whole kernel)
    __shared__ float sa2[64][8];                      // 2 KB   (P0..P2b)
    __shared__ __align__(16) float s_big[4224];       // 16.9 KB: sq / sw2 / sxw
    __shared__ float spart[128][9];                   // 4.6 KB (P2a..P3)
    __shared__ float s_small[544];                    // 2.2 KB: spts then satt

    float* sq   = s_big;     // sq[((g<<3)+nl)*65 + c2]          (P1..P2a)
    float* sw2  = s_big;     // sw2[((g2<<3)+nl)*196 + d]        (P2b passes)
    float* sxw  = s_big;     // sxw[((g<<3)+nl)*132 + c]         (P4..P5)
    float* spts = s_small;   // spts[(c3*8+nl)*16 + kk]          (P1..P2b)
    float* satt = s_small;   // satt[nl*68 + g*16 + kk]          (P3..P6)

    // ---- P0: idx + a2 ----
    if (tid < 128) sidx[tid] = idx[((size_t)b * NN + n0) * 16 + tid];
    for (int i = tid; i < 512; i += 256) {
        int c = i >> 3, nl = i & 7;
        sa2[c][nl] = abs_x[((size_t)b * 64 + c) * NN + n0 + nl];
    }
    __syncthreads();

    // ---- P1: points gather + q~ stage (thread = (g,row)) ----
    for (int i = tid; i < 384; i += 256) {
        int c3 = i >> 7, r = i & 127;
        spts[(c3 * 8 + (r >> 4)) * 16 + (r & 15)] =
            points[((size_t)b * 3 + c3) * NN + sidx[r]];
    }
    {
        const int g = tid >> 6, row = tid & 63;
        const float* qb = Qbuf + (((size_t)g * 64) << 8) + row;
        float a0 = 0.f, a1 = 0.f, a2v = 0.f, a3 = 0.f,
              a4 = 0.f, a5 = 0.f, a6 = 0.f, a7 = 0.f;
        for (int c2 = 0; c2 < 64; ++c2) {
            const float qv = qb[c2 << 8];
            const float4 v0 = *(const float4*)&sa2[c2][0];
            const float4 v1 = *(const float4*)&sa2[c2][4];
            a0 = fmaf(qv, v0.x, a0); a1 = fmaf(qv, v0.y, a1);
            a2v = fmaf(qv, v0.z, a2v); a3 = fmaf(qv, v0.w, a3);
            a4 = fmaf(qv, v1.x, a4); a5 = fmaf(qv, v1.y, a5);
            a6 = fmaf(qv, v1.z, a6); a7 = fmaf(qv, v1.w, a7);
        }
        const int base = (g << 3) * 65 + row;
        sq[base + 0 * 65] = a0; sq[base + 1 * 65] = a1;
        sq[base + 2 * 65] = a2v; sq[base + 3 * 65] = a3;
        sq[base + 4 * 65] = a4; sq[base + 5 * 65] = a5;
        sq[base + 6 * 65] = a6; sq[base + 7 * 65] = a7;
    }
    __syncthreads();

    // common thread mapping for P2a/P2b
    const int col = tid & 127, dh = tid >> 7;
    const int nlc = col >> 4, kkc = col & 15;

    // ---- P2a: logitA partials -> spart[col][dh*4+g] ----
    {
        const float* xp = x + (((size_t)(b * 128 + dh * 32) * NN) + n0 + nlc) * 16 + kkc;
        const float* q0 = &sq[((0 << 3) + nlc) * 65 + dh * 32];
        const float* q1 = &sq[((1 << 3) + nlc) * 65 + dh * 32];
        const float* q2 = &sq[((2 << 3) + nlc) * 65 + dh * 32];
        const float* q3 = &sq[((3 << 3) + nlc) * 65 + dh * 32];
        float a0 = 0.f, a1 = 0.f, a2v = 0.f, a3 = 0.f;
        for (int i = 0; i < 32; ++i) {
            const float xs = xp[0] + xp[(size_t)64 * NN * 16];
            xp += NN * 16;
            a0 = fmaf(q0[i], xs, a0);
            a1 = fmaf(q1[i], xs, a1);
            a2v = fmaf(q2[i], xs, a2v);
            a3 = fmaf(q3[i], xs, a3);
        }
        spart[col][dh * 4 + 0] = a0; spart[col][dh * 4 + 1] = a1;
        spart[col][dh * 4 + 2] = a2v; spart[col][dh * 4 + 3] = a3;
    }
    __syncthreads();   // sq dead; s_big free for sw2

    // ---- P2b: logitB in two 2-group passes (w~ staged 12.5 KB at a time) ----
    const float r0 = spts[(0 * 8 + nlc) * 16 + kkc] - spts[(0 * 8 + nlc) * 16];
    const float r1 = spts[(1 * 8 + nlc) * 16 + kkc] - spts[(1 * 8 + nlc) * 16];
    const float r2 = spts[(2 * 8 + nlc) * 16 + kkc] - spts[(2 * 8 + nlc) * 16];
    #pragma unroll
    for (int p = 0; p < 2; ++p) {
        if (tid < 192) {            // stage w~[2p..2p+1][tid(d)][8 nl]
            const int d = tid;
            float w00=0.f,w01=0.f,w02=0.f,w03=0.f,w04=0.f,w05=0.f,w06=0.f,w07=0.f;
            float w10=0.f,w11=0.f,w12=0.f,w13=0.f,w14=0.f,w15=0.f,w16=0.f,w17=0.f;
            const float* qb0 = Qbuf + (((size_t)(2 * p + 0) * 64) << 8) + 64 + d;
            const float* qb1 = Qbuf + (((size_t)(2 * p + 1) * 64) << 8) + 64 + d;
            for (int c2 = 0; c2 < 64; ++c2) {
                const float qv0 = qb0[c2 << 8];
                const float qv1 = qb1[c2 << 8];
                const float4 v0 = *(const float4*)&sa2[c2][0];
                const float4 v1 = *(const float4*)&sa2[c2][4];
                w00 = fmaf(qv0, v0.x, w00); w01 = fmaf(qv0, v0.y, w01);
                w02 = fmaf(qv0, v0.z, w02); w03 = fmaf(qv0, v0.w, w03);
                w04 = fmaf(qv0, v1.x, w04); w05 = fmaf(qv0, v1.y, w05);
                w06 = fmaf(qv0, v1.z, w06); w07 = fmaf(qv0, v1.w, w07);
                w10 = fmaf(qv1, v0.x, w10); w11 = fmaf(qv1, v0.y, w11);
                w12 = fmaf(qv1, v0.z, w12); w13 = fmaf(qv1, v0.w, w13);
                w14 = fmaf(qv1, v1.x, w14); w15 = fmaf(qv1, v1.y, w15);
                w16 = fmaf(qv1, v1.z, w16); w17 = fmaf(qv1, v1.w, w17);
            }
            sw2[(0 * 8 + 0) * 196 + d] = w00; sw2[(0 * 8 + 1) * 196 + d] = w01;
            sw2[(0 * 8 + 2) * 196 + d] = w02; sw2[(0 * 8 + 3) * 196 + d] = w03;
            sw2[(0 * 8 + 4) * 196 + d] = w04; sw2[(0 * 8 + 5) * 196 + d] = w05;
            sw2[(0 * 8 + 6) * 196 + d] = w06; sw2[(0 * 8 + 7) * 196 + d] = w07;
            sw2[(1 * 8 + 0) * 196 + d] = w10; sw2[(1 * 8 + 1) * 196 + d] = w11;
            sw2[(1 * 8 + 2) * 196 + d] = w12; sw2[(1 * 8 + 3) * 196 + d] = w13;
            sw2[(1 * 8 + 4) * 196 + d] = w14; sw2[(1 * 8 + 5) * 196 + d] = w15;
            sw2[(1 * 8 + 6) * 196 + d] = w16; sw2[(1 * 8 + 7) * 196 + d] = w17;
        }
        __syncthreads();
        {
            float pB0 = 0.f, pB1 = 0.f;
            const float* w0 = &sw2[(0 * 8 + nlc) * 196];
            const float* w1 = &sw2[(1 * 8 + nlc) * 196];
            const int d0 = dh * 96;
            for (int d = d0; d < d0 + 96; d += 4) {
                const float4 w1a = *(const float4*)&pe_w1[d];
                const float4 w1b = *(const float4*)&pe_w1[192 + d];
                const float4 w1c = *(const float4*)&pe_w1[384 + d];
                const float4 bb  = *(const float4*)&pe_b1[d];
                const float h0 = fmaxf(fmaf(r0, w1a.x, fmaf(r1, w1b.x, fmaf(r2, w1c.x, bb.x))), 0.f);
                const float h1 = fmaxf(fmaf(r0, w1a.y, fmaf(r1, w1b.y, fmaf(r2, w1c.y, bb.y))), 0.f);
                const float h2 = fmaxf(fmaf(r0, w1a.z, fmaf(r1, w1b.z, fmaf(r2, w1c.z, bb.z))), 0.f);
                const float h3 = fmaxf(fmaf(r0, w1a.w, fmaf(r1, w1b.w, fmaf(r2, w1c.w, bb.w))), 0.f);
                const float4 wa = *(const float4*)&w0[d];
                const float4 wb = *(const float4*)&w1[d];
                pB0 = fmaf(h0, wa.x, fmaf(h1, wa.y, fmaf(h2, wa.z, fmaf(h3, wa.w, pB0))));
                pB1 = fmaf(h0, wb.x, fmaf(h1, wb.y, fmaf(h2, wb.z, fmaf(h3, wb.w, pB1))));
            }
            spart[col][dh * 4 + 2 * p + 0] += pB0;
            spart[col][dh * 4 + 2 * p + 1] += pB1;
        }
        __syncthreads();
    }

    // ---- P3: softmax over kk per (g,nl) ----
    if (tid < 32) {
        const int g = tid >> 3, nl = tid & 7;
        float lg[16], m = -1e30f;
        #pragma unroll
        for (int kk = 0; kk < 16; ++kk) {
            const int cc = nl * 16 + kk;
            lg[kk] = spart[cc][g] + spart[cc][4 + g];
            m = fmaxf(m, lg[kk]);
        }
        float s = 0.f;
        #pragma unroll
        for (int kk = 0; kk < 16; ++kk) { lg[kk] = __expf(lg[kk] - m); s += lg[kk]; }
        const float inv = 1.f / s;
        #pragma unroll
        for (int kk = 0; kk < 16; ++kk) satt[nl * 68 + g * 16 + kk] = lg[kk] * inv;
    }
    __syncthreads();

    // ---- P4: xw[g][nl][c] = sum_kk x[c][nl*16+kk]*att ----
    #pragma unroll
    for (int t = 0; t < 4; ++t) {
        const int i2 = t * 256 + tid;
        const int c = i2 >> 3, nl = i2 & 7;
        const float* xp = x + (((size_t)(b * 128 + c) * NN) + n0 + nl) * 16;
        const float4 x0 = *(const float4*)(xp);
        const float4 x1 = *(const float4*)(xp + 4);
        const float4 x2 = *(const float4*)(xp + 8);
        const float4 x3 = *(const float4*)(xp + 12);
        const float* at = &satt[nl * 68];
        #pragma unroll
        for (int g = 0; g < 4; ++g) {
            const float* a = at + g * 16;
            float v = 0.f;
            v = fmaf(x0.x, a[0],  v); v = fmaf(x0.y, a[1],  v);
            v = fmaf(x0.z, a[2],  v); v = fmaf(x0.w, a[3],  v);
            v = fmaf(x1.x, a[4],  v); v = fmaf(x1.y, a[5],  v);
            v = fmaf(x1.z, a[6],  v); v = fmaf(x1.w, a[7],  v);
            v = fmaf(x2.x, a[8],  v); v = fmaf(x2.y, a[9],  v);
            v = fmaf(x2.z, a[10], v); v = fmaf(x2.w, a[11], v);
            v = fmaf(x3.x, a[12], v); v = fmaf(x3.y, a[13], v);
            v = fmaf(x3.z, a[14], v); v = fmaf(x3.w, a[15], v);
            sxw[((g << 3) + nl) * 132 + c] = v;
        }
    }
    __syncthreads();

    // ---- P5: out[o][n] = Wv[o,:] . xw[g(o)][nl][:] ----
    #pragma unroll
    for (int rep = 0; rep < 6; ++rep) {
        const int i = rep * 256 + tid;
        const int o = i >> 3, nl = i & 7;
        const int g = o / 48;
        const float* wv  = Wv + (size_t)o * 128;
        const float* xwp = &sxw[((g << 3) + nl) * 132];
        float a = 0.f;
        for (int c = 0; c < 128; c += 4) {
            const float4 w4  = *(const float4*)(wv + c);
            const float4 xw4 = *(const float4*)(xwp + c);
            a = fmaf(w4.x, xw4.x, fmaf(w4.y, xw4.y, fmaf(w4.z, xw4.z, fmaf(w4.w, xw4.w, a))));
        }
        out[(((size_t)b << 8) + o) * NN + n0 + nl] = a;
    }

    // ---- P6: deferred cent atomic scatter ----
    if (tid < 32) {
        const int g = tid >> 3, nl = tid & 7;
        #pragma unroll
        for (int kk = 0; kk < 16; ++kk)
            atomicAdd(&cent[((size_t)(b * GG + g) << 11) + sidx[nl * 16 + kk]],
                      satt[nl * 68 + g * 16 + kk]);
    }
}

// ---------------------------------------------------------------------------
// Kernel C: per (b,g): top-16 of cent row (512 threads), then nonlocal prep.
// ---------------------------------------------------------------------------
__global__ __launch_bounds__(512) void topk_prep_kernel(
    const float* __restrict__ abs_x, const float* __restrict__ points,
    const float* __restrict__ Wnk, const float* __restrict__ Wnv2,
    const float* __restrict__ npe_w1, const float* __restrict__ npe_b1,
    const float* __restrict__ npe_w2, const float* __restrict__ npe_b2,
    const float* __restrict__ cent,
    float* __restrict__ nkpe, float* __restrict__ nv2j, float* __restrict__ tanhv)
{
    const int bg  = blockIdx.x;
    const int b   = bg >> 2, g = bg & 3;
    const int tid = threadIdx.x;
    __shared__ float sc[2048];
    __shared__ float rv[8];  __shared__ int ri[8];
    __shared__ float svals[16]; __shared__ int sinds[16];
    __shared__ float srel[3][16];
    __shared__ float sh2[16][16];

    for (int i = tid; i < 2048; i += 512) sc[i] = cent[((size_t)bg << 11) + i];
    __syncthreads();
    for (int t = 0; t < 16; ++t) {
        float bv = -1e30f; int bi = 1 << 30;
        for (int i = tid; i < 2048; i += 512) {      // ascending -> lowest idx on ties
            float v = sc[i];
            if (v > bv) { bv = v; bi = i; }
        }
        #pragma unroll
        for (int off = 1; off < 64; off <<= 1) {
            float ov = __shfl_xor(bv, off, 64);
            int   oi = __shfl_xor(bi, off, 64);
            if (ov > bv || (ov == bv && oi < bi)) { bv = ov; bi = oi; }
        }
        if ((tid & 63) == 0) { rv[tid >> 6] = bv; ri[tid >> 6] = bi; }
        __syncthreads();
        if (tid == 0) {
            for (int w = 1; w < 8; ++w)
                if (rv[w] > bv || (rv[w] == bv && ri[w] < bi)) { bv = rv[w]; bi = ri[w]; }
            svals[t] = bv; sinds[t] = bi;
            sc[bi] = -1e30f;
        }
        __syncthreads();
    }

    if (tid < 48) {
        int c = tid >> 4, j = tid & 15;
        srel[c][j] = points[((size_t)b * 3 + c) * NN + sinds[j]]
                   - points[((size_t)b * 3 + c) * NN + sinds[0]];
    }
    __syncthreads();
    if (tid < 256) {
        int j = tid >> 4, d = tid & 15;
        float a = npe_b1[g * 16 + d];
        #pragma unroll
        for (int c = 0; c < 3; ++c) a = fmaf(srel[c][j], npe_w1[((g * 3 + c) << 4) + d], a);
        sh2[j][d] = fmaxf(a, 0.f);
    }
    __syncthreads();
    if (tid < 256) {
        int c = tid >> 4, j = tid & 15;
        float a = npe_b2[g * 16 + c];
        #pragma unroll
        for (int d = 0; d < 16; ++d) a = fmaf(sh2[j][d], npe_w2[((g * 16 + d) << 4) + c], a);
        float nk = 0.f, nv = 0.f;
        const int colj = sinds[j];
        const float* a2  = abs_x + (size_t)b * 64 * NN + colj;
        const float* wkr = Wnk  + ((size_t)(g * 16 + c) << 6);
        const float* wvr = Wnv2 + ((size_t)(g * 16 + c) << 6);
        for (int ci = 0; ci < 64; ++ci) {
            float av = a2[(size_t)ci * NN];
            nk = fmaf(wkr[ci], av, nk);
            nv = fmaf(wvr[ci], av, nv);
        }
        nkpe[((size_t)bg << 8) + (c << 4) + j] = nk + a;
        nv2j[((size_t)bg << 8) + (c << 4) + j] = nv;
    }
    if (tid < 16) tanhv[(bg << 4) + tid] = tanhf(svals[tid]);
}

// ---------------------------------------------------------------------------
// Kernel D: nonlocal branch (unchanged).
// ---------------------------------------------------------------------------
__global__ __launch_bounds__(256) void nonlocal_kernel(
    const float* __restrict__ abs_x,
    const float* __restrict__ Wnq, const float* __restrict__ Wnv1, const float* __restrict__ Wnv2,
    const float* __restrict__ nkpe, const float* __restrict__ nv2j, const float* __restrict__ tanhv,
    float* __restrict__ out)
{
    const int blk = blockIdx.x;
    const int b   = blk >> 5;
    const int n0  = (blk & 31) << 6;
    const int tid = threadIdx.x;
    const int nl  = tid & 63;
    const int g   = tid >> 6;

    __shared__ float sa2[64][64];
    __shared__ float snkpe[4][16][16];
    __shared__ float snv2j[4][16][16];
    __shared__ float stanh[4][16];

    for (int i = tid; i < 64 * 64; i += 256) {
        int ci = i >> 6, c2 = i & 63;
        sa2[ci][c2] = abs_x[((size_t)b * 64 + ci) * NN + n0 + c2];
    }
    for (int i = tid; i < 1024; i += 256) {
        ((float*)snkpe)[i] = nkpe[((size_t)b << 10) + i];
        ((float*)snv2j)[i] = nv2j[((size_t)b << 10) + i];
    }
    if (tid < 64) ((float*)stanh)[tid] = tanhv[(b << 6) + tid];
    __syncthreads();

    float nq[16], nv1[16], nv2[16];
    #pragma unroll
    for (int c = 0; c < 16; ++c) { nq[c] = 0.f; nv1[c] = 0.f; nv2[c] = 0.f; }
    const float* wq  = Wnq  + (size_t)(g << 4) * 64;
    const float* wv1 = Wnv1 + (size_t)(g << 4) * 64;
    const float* wv2 = Wnv2 + (size_t)(g << 4) * 64;
    for (int ci = 0; ci < 64; ++ci) {
        const float a = sa2[ci][nl];
        #pragma unroll
        for (int c = 0; c < 16; ++c) {
            nq[c]  = fmaf(wq [(c << 6) + ci], a, nq[c]);
            nv1[c] = fmaf(wv1[(c << 6) + ci], a, nv1[c]);
            nv2[c] = fmaf(wv2[(c << 6) + ci], a, nv2[c]);
        }
    }

    float lg[16];
    #pragma unroll
    for (int j = 0; j < 16; ++j) {
        float a = 0.f;
        #pragma unroll
        for (int c = 0; c < 16; ++c) a = fmaf(nq[c], snkpe[g][c][j], a);
        lg[j] = a;
    }
    float m = lg[0];
    #pragma unroll
    for (int j = 1; j < 16; ++j) m = fmaxf(m, lg[j]);
    float s = 0.f;
    float w[16];
    #pragma unroll
    for (int j = 0; j < 16; ++j) { w[j] = __expf(lg[j] - m); s += w[j]; }
    const float inv = 1.f / s;
    float ws = 0.f;
    #pragma unroll
    for (int j = 0; j < 16; ++j) { w[j] = w[j] * inv * stanh[g][j]; ws += w[j]; }
    #pragma unroll
    for (int c = 0; c < 16; ++c) {
        float v = (nv1[c] - nv2[c]) * ws;
        #pragma unroll
        for (int j = 0; j < 16; ++j) v = fmaf(w[j], snv2j[g][c][j], v);
        out[(((size_t)b << 8) + 192 + (g << 4) + c) * NN + n0 + nl] = v;
    }
}

// ---------------------------------------------------------------------------
extern "C" void kernel_launch(void* const* d_in, const int* in_sizes, int n_in,
                              void* d_out, int out_size, void* d_ws, size_t ws_size,
                              hipStream_t stream)
{
    (void)in_sizes; (void)n_in; (void)out_size; (void)ws_size;
    const float* x      = (const float*)d_in[0];
    const float* abs_x  = (const float*)d_in[1];
    const float* points = (const float*)d_in[2];
    const float* Wq     = (const float*)d_in[3];
    const float* Wk     = (const float*)d_in[4];
    const float* Wv     = (const float*)d_in[5];
    const float* Wnq    = (const float*)d_in[6];
    const float* Wnk    = (const float*)d_in[7];
    const float* Wnv1   = (const float*)d_in[8];
    const float* Wnv2   = (const float*)d_in[9];
    const float* pe_w1  = (const float*)d_in[10];
    const float* pe_b1  = (const float*)d_in[11];
    const float* pe_w2  = (const float*)d_in[12];
    // pe_b2 (d_in[13]): constant logit shift per (g,n) -> cancels in softmax
    const float* npe_w1 = (const float*)d_in[14];
    const float* npe_b1 = (const float*)d_in[15];
    const float* npe_w2 = (const float*)d_in[16];
    const float* npe_b2 = (const float*)d_in[17];
    const int*   idx    = (const int*)d_in[18];
    float* out = (float*)d_out;

    // ws layout (floats): cent[65536] | Qbuf[65536] | nkpe[8192] | nv2j[8192] | tanh[512]
    float* cent  = (float*)d_ws;
    float* Qbuf  = cent + 65536;
    float* nkpeW = Qbuf + 65536;
    float* nv2jW = nkpeW + 8192;
    float* tanhW = nv2jW + 8192;

    hipMemsetAsync(cent, 0, (size_t)65536 * sizeof(float), stream);
    prep_q<<<256, 256, 0, stream>>>(Wq, Wk, pe_w2, Qbuf);
    local_v7b<<<2048, 256, 0, stream>>>(x, abs_x, points, Wv, pe_w1, pe_b1,
                                        idx, Qbuf, out, cent);
    topk_prep_kernel<<<32, 512, 0, stream>>>(abs_x, points, Wnk, Wnv2,
                                             npe_w1, npe_b1, npe_w2, npe_b2,
                                             cent, nkpeW, nv2jW, tanhW);
    nonlocal_kernel<<<8 * 32, 256, 0, stream>>>(abs_x, Wnq, Wnv1, Wnv2,
                                                nkpeW, nv2jW, tanhW, out);
}

// Round 9
// 241.275 us; speedup vs baseline: 2.6575x; 1.0858x over previous
//
#include <hip/hip_runtime.h>
#include <cstddef>

// Shapes: B=8, CIN=128, N=2048, K=16, G=4, COUT=256, L=192, CL=48, NL=64, CNL=16
constexpr int NN = 2048;
constexpr int GG = 4;

// ---------------------------------------------------------------------------
// prep_q: Qbuf[g][c2][row] f32 (row<64: M_g[row][c2] = sum_o Wk[o][row]Wq[o][c2];
// row>=64: W2q_g[row-64][c2] = sum_o pe_w2[row-64][o]Wq[o][c2]), o in group g.
// ---------------------------------------------------------------------------
__global__ __launch_bounds__(256) void prep_q(const float* __restrict__ Wq,
                                              const float* __restrict__ Wk,
                                              const float* __restrict__ pe_w2,
                                              float* __restrict__ Qbuf) {
    const int g = blockIdx.x >> 6, c2 = blockIdx.x & 63;
    const int row = threadIdx.x;
    float acc = 0.f;
    if (row < 64) {
        for (int j = 0; j < 48; ++j) {
            const int o = g * 48 + j;
            acc = fmaf(Wk[o * 64 + row], Wq[o * 64 + c2], acc);
        }
    } else {
        const int d = row - 64;
        for (int j = 0; j < 48; ++j) {
            const int o = g * 48 + j;
            acc = fmaf(pe_w2[(size_t)d * 192 + o], Wq[o * 64 + c2], acc);
        }
    }
    Qbuf[((size_t)(g * 64 + c2) << 8) + row] = acc;
}

// ---------------------------------------------------------------------------
// local_v7c: v7b structure, launch_bounds(256,3) -> allocator unconstrained
// (v4 empirically: 84 VGPR, zero spill). LDS 26.6KB -> occupancy then
// LDS/VGPR-limited at ~6 blocks/CU. All logit math f32 (top-k safe).
// Block = (b, 8 n), 256 threads.
// ---------------------------------------------------------------------------
__global__ __launch_bounds__(256, 3) void local_v7c(
    const float* __restrict__ x, const float* __restrict__ abs_x,
    const float* __restrict__ points, const float* __restrict__ Wv,
    const float* __restrict__ pe_w1, const float* __restrict__ pe_b1,
    const int* __restrict__ idx, const float* __restrict__ Qbuf,
    float* __restrict__ out, float* __restrict__ cent)
{
    const int bn = blockIdx.x;           // 2048 blocks
    const int b  = bn >> 8;
    const int n0 = (bn & 255) << 3;
    const int tid = threadIdx.x;

    __shared__ int   sidx[128];                       // 0.5 KB (whole kernel)
    __shared__ float sa2[64][8];                      // 2 KB   (P0..P2b)
    __shared__ __align__(16) float s_big[4224];       // 16.9 KB: sq / sw2 / sxw
    __shared__ float spart[128][9];                   // 4.6 KB (P2a..P3)
    __shared__ float s_small[544];                    // 2.2 KB: spts then satt

    float* sq   = s_big;     // sq[((g<<3)+nl)*65 + c2]          (P1..P2a)
    float* sw2  = s_big;     // sw2[((g2<<3)+nl)*196 + d]        (P2b passes)
    float* sxw  = s_big;     // sxw[((g<<3)+nl)*132 + c]         (P4..P5)
    float* spts = s_small;   // spts[(c3*8+nl)*16 + kk]          (P1..P2b)
    float* satt = s_small;   // satt[nl*68 + g*16 + kk]          (P3..P6)

    // ---- P0: idx + a2 ----
    if (tid < 128) sidx[tid] = idx[((size_t)b * NN + n0) * 16 + tid];
    for (int i = tid; i < 512; i += 256) {
        int c = i >> 3, nl = i & 7;
        sa2[c][nl] = abs_x[((size_t)b * 64 + c) * NN + n0 + nl];
    }
    __syncthreads();

    // ---- P1: points gather + q~ stage (thread = (g,row)) ----
    for (int i = tid; i < 384; i += 256) {
        int c3 = i >> 7, r = i & 127;
        spts[(c3 * 8 + (r >> 4)) * 16 + (r & 15)] =
            points[((size_t)b * 3 + c3) * NN + sidx[r]];
    }
    {
        const int g = tid >> 6, row = tid & 63;
        const float* qb = Qbuf + (((size_t)g * 64) << 8) + row;
        float a0 = 0.f, a1 = 0.f, a2v = 0.f, a3 = 0.f,
              a4 = 0.f, a5 = 0.f, a6 = 0.f, a7 = 0.f;
        for (int c2 = 0; c2 < 64; ++c2) {
            const float qv = qb[c2 << 8];
            const float4 v0 = *(const float4*)&sa2[c2][0];
            const float4 v1 = *(const float4*)&sa2[c2][4];
            a0 = fmaf(qv, v0.x, a0); a1 = fmaf(qv, v0.y, a1);
            a2v = fmaf(qv, v0.z, a2v); a3 = fmaf(qv, v0.w, a3);
            a4 = fmaf(qv, v1.x, a4); a5 = fmaf(qv, v1.y, a5);
            a6 = fmaf(qv, v1.z, a6); a7 = fmaf(qv, v1.w, a7);
        }
        const int base = (g << 3) * 65 + row;
        sq[base + 0 * 65] = a0; sq[base + 1 * 65] = a1;
        sq[base + 2 * 65] = a2v; sq[base + 3 * 65] = a3;
        sq[base + 4 * 65] = a4; sq[base + 5 * 65] = a5;
        sq[base + 6 * 65] = a6; sq[base + 7 * 65] = a7;
    }
    __syncthreads();

    // common thread mapping for P2a/P2b
    const int col = tid & 127, dh = tid >> 7;
    const int nlc = col >> 4, kkc = col & 15;

    // ---- P2a: logitA partials -> spart[col][dh*4+g] ----
    {
        const float* xp = x + (((size_t)(b * 128 + dh * 32) * NN) + n0 + nlc) * 16 + kkc;
        const float* q0 = &sq[((0 << 3) + nlc) * 65 + dh * 32];
        const float* q1 = &sq[((1 << 3) + nlc) * 65 + dh * 32];
        const float* q2 = &sq[((2 << 3) + nlc) * 65 + dh * 32];
        const float* q3 = &sq[((3 << 3) + nlc) * 65 + dh * 32];
        float a0 = 0.f, a1 = 0.f, a2v = 0.f, a3 = 0.f;
        for (int i = 0; i < 32; ++i) {
            const float xs = xp[0] + xp[(size_t)64 * NN * 16];
            xp += NN * 16;
            a0 = fmaf(q0[i], xs, a0);
            a1 = fmaf(q1[i], xs, a1);
            a2v = fmaf(q2[i], xs, a2v);
            a3 = fmaf(q3[i], xs, a3);
        }
        spart[col][dh * 4 + 0] = a0; spart[col][dh * 4 + 1] = a1;
        spart[col][dh * 4 + 2] = a2v; spart[col][dh * 4 + 3] = a3;
    }
    __syncthreads();   // sq dead; s_big free for sw2

    // ---- P2b: logitB in two 2-group passes (w~ staged 12.5 KB at a time) ----
    const float r0 = spts[(0 * 8 + nlc) * 16 + kkc] - spts[(0 * 8 + nlc) * 16];
    const float r1 = spts[(1 * 8 + nlc) * 16 + kkc] - spts[(1 * 8 + nlc) * 16];
    const float r2 = spts[(2 * 8 + nlc) * 16 + kkc] - spts[(2 * 8 + nlc) * 16];
    #pragma unroll
    for (int p = 0; p < 2; ++p) {
        if (tid < 192) {            // stage w~[2p..2p+1][tid(d)][8 nl]
            const int d = tid;
            float w00=0.f,w01=0.f,w02=0.f,w03=0.f,w04=0.f,w05=0.f,w06=0.f,w07=0.f;
            float w10=0.f,w11=0.f,w12=0.f,w13=0.f,w14=0.f,w15=0.f,w16=0.f,w17=0.f;
            const float* qb0 = Qbuf + (((size_t)(2 * p + 0) * 64) << 8) + 64 + d;
            const float* qb1 = Qbuf + (((size_t)(2 * p + 1) * 64) << 8) + 64 + d;
            for (int c2 = 0; c2 < 64; ++c2) {
                const float qv0 = qb0[c2 << 8];
                const float qv1 = qb1[c2 << 8];
                const float4 v0 = *(const float4*)&sa2[c2][0];
                const float4 v1 = *(const float4*)&sa2[c2][4];
                w00 = fmaf(qv0, v0.x, w00); w01 = fmaf(qv0, v0.y, w01);
                w02 = fmaf(qv0, v0.z, w02); w03 = fmaf(qv0, v0.w, w03);
                w04 = fmaf(qv0, v1.x, w04); w05 = fmaf(qv0, v1.y, w05);
                w06 = fmaf(qv0, v1.z, w06); w07 = fmaf(qv0, v1.w, w07);
                w10 = fmaf(qv1, v0.x, w10); w11 = fmaf(qv1, v0.y, w11);
                w12 = fmaf(qv1, v0.z, w12); w13 = fmaf(qv1, v0.w, w13);
                w14 = fmaf(qv1, v1.x, w14); w15 = fmaf(qv1, v1.y, w15);
                w16 = fmaf(qv1, v1.z, w16); w17 = fmaf(qv1, v1.w, w17);
            }
            sw2[(0 * 8 + 0) * 196 + d] = w00; sw2[(0 * 8 + 1) * 196 + d] = w01;
            sw2[(0 * 8 + 2) * 196 + d] = w02; sw2[(0 * 8 + 3) * 196 + d] = w03;
            sw2[(0 * 8 + 4) * 196 + d] = w04; sw2[(0 * 8 + 5) * 196 + d] = w05;
            sw2[(0 * 8 + 6) * 196 + d] = w06; sw2[(0 * 8 + 7) * 196 + d] = w07;
            sw2[(1 * 8 + 0) * 196 + d] = w10; sw2[(1 * 8 + 1) * 196 + d] = w11;
            sw2[(1 * 8 + 2) * 196 + d] = w12; sw2[(1 * 8 + 3) * 196 + d] = w13;
            sw2[(1 * 8 + 4) * 196 + d] = w14; sw2[(1 * 8 + 5) * 196 + d] = w15;
            sw2[(1 * 8 + 6) * 196 + d] = w16; sw2[(1 * 8 + 7) * 196 + d] = w17;
        }
        __syncthreads();
        {
            float pB0 = 0.f, pB1 = 0.f;
            const float* w0 = &sw2[(0 * 8 + nlc) * 196];
            const float* w1 = &sw2[(1 * 8 + nlc) * 196];
            const int d0 = dh * 96;
            for (int d = d0; d < d0 + 96; d += 4) {
                const float4 w1a = *(const float4*)&pe_w1[d];
                const float4 w1b = *(const float4*)&pe_w1[192 + d];
                const float4 w1c = *(const float4*)&pe_w1[384 + d];
                const float4 bb  = *(const float4*)&pe_b1[d];
                const float h0 = fmaxf(fmaf(r0, w1a.x, fmaf(r1, w1b.x, fmaf(r2, w1c.x, bb.x))), 0.f);
                const float h1 = fmaxf(fmaf(r0, w1a.y, fmaf(r1, w1b.y, fmaf(r2, w1c.y, bb.y))), 0.f);
                const float h2 = fmaxf(fmaf(r0, w1a.z, fmaf(r1, w1b.z, fmaf(r2, w1c.z, bb.z))), 0.f);
                const float h3 = fmaxf(fmaf(r0, w1a.w, fmaf(r1, w1b.w, fmaf(r2, w1c.w, bb.w))), 0.f);
                const float4 wa = *(const float4*)&w0[d];
                const float4 wb = *(const float4*)&w1[d];
                pB0 = fmaf(h0, wa.x, fmaf(h1, wa.y, fmaf(h2, wa.z, fmaf(h3, wa.w, pB0))));
                pB1 = fmaf(h0, wb.x, fmaf(h1, wb.y, fmaf(h2, wb.z, fmaf(h3, wb.w, pB1))));
            }
            spart[col][dh * 4 + 2 * p + 0] += pB0;
            spart[col][dh * 4 + 2 * p + 1] += pB1;
        }
        __syncthreads();
    }

    // ---- P3: softmax over kk per (g,nl) ----
    if (tid < 32) {
        const int g = tid >> 3, nl = tid & 7;
        float lg[16], m = -1e30f;
        #pragma unroll
        for (int kk = 0; kk < 16; ++kk) {
            const int cc = nl * 16 + kk;
            lg[kk] = spart[cc][g] + spart[cc][4 + g];
            m = fmaxf(m, lg[kk]);
        }
        float s = 0.f;
        #pragma unroll
        for (int kk = 0; kk < 16; ++kk) { lg[kk] = __expf(lg[kk] - m); s += lg[kk]; }
        const float inv = 1.f / s;
        #pragma unroll
        for (int kk = 0; kk < 16; ++kk) satt[nl * 68 + g * 16 + kk] = lg[kk] * inv;
    }
    __syncthreads();

    // ---- P4: xw[g][nl][c] = sum_kk x[c][nl*16+kk]*att ----
    #pragma unroll
    for (int t = 0; t < 4; ++t) {
        const int i2 = t * 256 + tid;
        const int c = i2 >> 3, nl = i2 & 7;
        const float* xp = x + (((size_t)(b * 128 + c) * NN) + n0 + nl) * 16;
        const float4 x0 = *(const float4*)(xp);
        const float4 x1 = *(const float4*)(xp + 4);
        const float4 x2 = *(const float4*)(xp + 8);
        const float4 x3 = *(const float4*)(xp + 12);
        const float* at = &satt[nl * 68];
        #pragma unroll
        for (int g = 0; g < 4; ++g) {
            const float* a = at + g * 16;
            float v = 0.f;
            v = fmaf(x0.x, a[0],  v); v = fmaf(x0.y, a[1],  v);
            v = fmaf(x0.z, a[2],  v); v = fmaf(x0.w, a[3],  v);
            v = fmaf(x1.x, a[4],  v); v = fmaf(x1.y, a[5],  v);
            v = fmaf(x1.z, a[6],  v); v = fmaf(x1.w, a[7],  v);
            v = fmaf(x2.x, a[8],  v); v = fmaf(x2.y, a[9],  v);
            v = fmaf(x2.z, a[10], v); v = fmaf(x2.w, a[11], v);
            v = fmaf(x3.x, a[12], v); v = fmaf(x3.y, a[13], v);
            v = fmaf(x3.z, a[14], v); v = fmaf(x3.w, a[15], v);
            sxw[((g << 3) + nl) * 132 + c] = v;
        }
    }
    __syncthreads();

    // ---- P5: out[o][n] = Wv[o,:] . xw[g(o)][nl][:] ----
    #pragma unroll
    for (int rep = 0; rep < 6; ++rep) {
        const int i = rep * 256 + tid;
        const int o = i >> 3, nl = i & 7;
        const int g = o / 48;
        const float* wv  = Wv + (size_t)o * 128;
        const float* xwp = &sxw[((g << 3) + nl) * 132];
        float a = 0.f;
        for (int c = 0; c < 128; c += 4) {
            const float4 w4  = *(const float4*)(wv + c);
            const float4 xw4 = *(const float4*)(xwp + c);
            a = fmaf(w4.x, xw4.x, fmaf(w4.y, xw4.y, fmaf(w4.z, xw4.z, fmaf(w4.w, xw4.w, a))));
        }
        out[(((size_t)b << 8) + o) * NN + n0 + nl] = a;
    }

    // ---- P6: deferred cent atomic scatter ----
    if (tid < 32) {
        const int g = tid >> 3, nl = tid & 7;
        #pragma unroll
        for (int kk = 0; kk < 16; ++kk)
            atomicAdd(&cent[((size_t)(b * GG + g) << 11) + sidx[nl * 16 + kk]],
                      satt[nl * 68 + g * 16 + kk]);
    }
}

// ---------------------------------------------------------------------------
// Kernel C: per (b,g): top-16 of cent row (512 threads), then nonlocal prep.
// ---------------------------------------------------------------------------
__global__ __launch_bounds__(512) void topk_prep_kernel(
    const float* __restrict__ abs_x, const float* __restrict__ points,
    const float* __restrict__ Wnk, const float* __restrict__ Wnv2,
    const float* __restrict__ npe_w1, const float* __restrict__ npe_b1,
    const float* __restrict__ npe_w2, const float* __restrict__ npe_b2,
    const float* __restrict__ cent,
    float* __restrict__ nkpe, float* __restrict__ nv2j, float* __restrict__ tanhv)
{
    const int bg  = blockIdx.x;
    const int b   = bg >> 2, g = bg & 3;
    const int tid = threadIdx.x;
    __shared__ float sc[2048];
    __shared__ float rv[8];  __shared__ int ri[8];
    __shared__ float svals[16]; __shared__ int sinds[16];
    __shared__ float srel[3][16];
    __shared__ float sh2[16][16];

    for (int i = tid; i < 2048; i += 512) sc[i] = cent[((size_t)bg << 11) + i];
    __syncthreads();
    for (int t = 0; t < 16; ++t) {
        float bv = -1e30f; int bi = 1 << 30;
        for (int i = tid; i < 2048; i += 512) {      // ascending -> lowest idx on ties
            float v = sc[i];
            if (v > bv) { bv = v; bi = i; }
        }
        #pragma unroll
        for (int off = 1; off < 64; off <<= 1) {
            float ov = __shfl_xor(bv, off, 64);
            int   oi = __shfl_xor(bi, off, 64);
            if (ov > bv || (ov == bv && oi < bi)) { bv = ov; bi = oi; }
        }
        if ((tid & 63) == 0) { rv[tid >> 6] = bv; ri[tid >> 6] = bi; }
        __syncthreads();
        if (tid == 0) {
            for (int w = 1; w < 8; ++w)
                if (rv[w] > bv || (rv[w] == bv && ri[w] < bi)) { bv = rv[w]; bi = ri[w]; }
            svals[t] = bv; sinds[t] = bi;
            sc[bi] = -1e30f;
        }
        __syncthreads();
    }

    if (tid < 48) {
        int c = tid >> 4, j = tid & 15;
        srel[c][j] = points[((size_t)b * 3 + c) * NN + sinds[j]]
                   - points[((size_t)b * 3 + c) * NN + sinds[0]];
    }
    __syncthreads();
    if (tid < 256) {
        int j = tid >> 4, d = tid & 15;
        float a = npe_b1[g * 16 + d];
        #pragma unroll
        for (int c = 0; c < 3; ++c) a = fmaf(srel[c][j], npe_w1[((g * 3 + c) << 4) + d], a);
        sh2[j][d] = fmaxf(a, 0.f);
    }
    __syncthreads();
    if (tid < 256) {
        int c = tid >> 4, j = tid & 15;
        float a = npe_b2[g * 16 + c];
        #pragma unroll
        for (int d = 0; d < 16; ++d) a = fmaf(sh2[j][d], npe_w2[((g * 16 + d) << 4) + c], a);
        float nk = 0.f, nv = 0.f;
        const int colj = sinds[j];
        const float* a2  = abs_x + (size_t)b * 64 * NN + colj;
        const float* wkr = Wnk  + ((size_t)(g * 16 + c) << 6);
        const float* wvr = Wnv2 + ((size_t)(g * 16 + c) << 6);
        for (int ci = 0; ci < 64; ++ci) {
            float av = a2[(size_t)ci * NN];
            nk = fmaf(wkr[ci], av, nk);
            nv = fmaf(wvr[ci], av, nv);
        }
        nkpe[((size_t)bg << 8) + (c << 4) + j] = nk + a;
        nv2j[((size_t)bg << 8) + (c << 4) + j] = nv;
    }
    if (tid < 16) tanhv[(bg << 4) + tid] = tanhf(svals[tid]);
}

// ---------------------------------------------------------------------------
// Kernel D: nonlocal branch (unchanged).
// ---------------------------------------------------------------------------
__global__ __launch_bounds__(256) void nonlocal_kernel(
    const float* __restrict__ abs_x,
    const float* __restrict__ Wnq, const float* __restrict__ Wnv1, const float* __restrict__ Wnv2,
    const float* __restrict__ nkpe, const float* __restrict__ nv2j, const float* __restrict__ tanhv,
    float* __restrict__ out)
{
    const int blk = blockIdx.x;
    const int b   = blk >> 5;
    const int n0  = (blk & 31) << 6;
    const int tid = threadIdx.x;
    const int nl  = tid & 63;
    const int g   = tid >> 6;

    __shared__ float sa2[64][64];
    __shared__ float snkpe[4][16][16];
    __shared__ float snv2j[4][16][16];
    __shared__ float stanh[4][16];

    for (int i = tid; i < 64 * 64; i += 256) {
        int ci = i >> 6, c2 = i & 63;
        sa2[ci][c2] = abs_x[((size_t)b * 64 + ci) * NN + n0 + c2];
    }
    for (int i = tid; i < 1024; i += 256) {
        ((float*)snkpe)[i] = nkpe[((size_t)b << 10) + i];
        ((float*)snv2j)[i] = nv2j[((size_t)b << 10) + i];
    }
    if (tid < 64) ((float*)stanh)[tid] = tanhv[(b << 6) + tid];
    __syncthreads();

    float nq[16], nv1[16], nv2[16];
    #pragma unroll
    for (int c = 0; c < 16; ++c) { nq[c] = 0.f; nv1[c] = 0.f; nv2[c] = 0.f; }
    const float* wq  = Wnq  + (size_t)(g << 4) * 64;
    const float* wv1 = Wnv1 + (size_t)(g << 4) * 64;
    const float* wv2 = Wnv2 + (size_t)(g << 4) * 64;
    for (int ci = 0; ci < 64; ++ci) {
        const float a = sa2[ci][nl];
        #pragma unroll
        for (int c = 0; c < 16; ++c) {
            nq[c]  = fmaf(wq [(c << 6) + ci], a, nq[c]);
            nv1[c] = fmaf(wv1[(c << 6) + ci], a, nv1[c]);
            nv2[c] = fmaf(wv2[(c << 6) + ci], a, nv2[c]);
        }
    }

    float lg[16];
    #pragma unroll
    for (int j = 0; j < 16; ++j) {
        float a = 0.f;
        #pragma unroll
        for (int c = 0; c < 16; ++c) a = fmaf(nq[c], snkpe[g][c][j], a);
        lg[j] = a;
    }
    float m = lg[0];
    #pragma unroll
    for (int j = 1; j < 16; ++j) m = fmaxf(m, lg[j]);
    float s = 0.f;
    float w[16];
    #pragma unroll
    for (int j = 0; j < 16; ++j) { w[j] = __expf(lg[j] - m); s += w[j]; }
    const float inv = 1.f / s;
    float ws = 0.f;
    #pragma unroll
    for (int j = 0; j < 16; ++j) { w[j] = w[j] * inv * stanh[g][j]; ws += w[j]; }
    #pragma unroll
    for (int c = 0; c < 16; ++c) {
        float v = (nv1[c] - nv2[c]) * ws;
        #pragma unroll
        for (int j = 0; j < 16; ++j) v = fmaf(w[j], snv2j[g][c][j], v);
        out[(((size_t)b << 8) + 192 + (g << 4) + c) * NN + n0 + nl] = v;
    }
}

// ---------------------------------------------------------------------------
extern "C" void kernel_launch(void* const* d_in, const int* in_sizes, int n_in,
                              void* d_out, int out_size, void* d_ws, size_t ws_size,
                              hipStream_t stream)
{
    (void)in_sizes; (void)n_in; (void)out_size; (void)ws_size;
    const float* x      = (const float*)d_in[0];
    const float* abs_x  = (const float*)d_in[1];
    const float* points = (const float*)d_in[2];
    const float* Wq     = (const float*)d_in[3];
    const float* Wk     = (const float*)d_in[4];
    const float* Wv     = (const float*)d_in[5];
    const float* Wnq    = (const float*)d_in[6];
    const float* Wnk    = (const float*)d_in[7];
    const float* Wnv1   = (const float*)d_in[8];
    const float* Wnv2   = (const float*)d_in[9];
    const float* pe_w1  = (const float*)d_in[10];
    const float* pe_b1  = (const float*)d_in[11];
    const float* pe_w2  = (const float*)d_in[12];
    // pe_b2 (d_in[13]): constant logit shift per (g,n) -> cancels in softmax
    const float* npe_w1 = (const float*)d_in[14];
    const float* npe_b1 = (const float*)d_in[15];
    const float* npe_w2 = (const float*)d_in[16];
    const float* npe_b2 = (const float*)d_in[17];
    const int*   idx    = (const int*)d_in[18];
    float* out = (float*)d_out;

    // ws layout (floats): cent[65536] | Qbuf[65536] | nkpe[8192] | nv2j[8192] | tanh[512]
    float* cent  = (float*)d_ws;
    float* Qbuf  = cent + 65536;
    float* nkpeW = Qbuf + 65536;
    float* nv2jW = nkpeW + 8192;
    float* tanhW = nv2jW + 8192;

    hipMemsetAsync(cent, 0, (size_t)65536 * sizeof(float), stream);
    prep_q<<<256, 256, 0, stream>>>(Wq, Wk, pe_w2, Qbuf);
    local_v7c<<<2048, 256, 0, stream>>>(x, abs_x, points, Wv, pe_w1, pe_b1,
                                        idx, Qbuf, out, cent);
    topk_prep_kernel<<<32, 512, 0, stream>>>(abs_x, points, Wnk, Wnv2,
                                             npe_w1, npe_b1, npe_w2, npe_b2,
                                             cent, nkpeW, nv2jW, tanhW);
    nonlocal_kernel<<<8 * 32, 256, 0, stream>>>(abs_x, Wnq, Wnv1, Wnv2,
                                                nkpeW, nv2jW, tanhW, out);
}